// Round 11
// baseline (801.047 us; speedup 1.0000x reference)
//
#include <hip/hip_runtime.h>
#include <math.h>

#define Sdim 64
#define Vdim 16
#define NLAYER 5
#define EDdim 16
#define RDdim 16
#define TDdim 64
#define FINdim 160   // 2*S + RD + ED
#define Hdim 96      // S + 2*V
#define NVdim 48     // 3*V
#define ACCW 113     // 64 ms + 48 vm + pad
#define HPAD 98      // hS row stride in floats (2-way banked = free)
#define VSW 52       // vS row stride in floats
#define GW 8         // nodes per block (3 waves)

typedef __attribute__((ext_vector_type(8))) short bf16x8;
typedef __attribute__((ext_vector_type(4))) float f32x4;

__device__ __forceinline__ float silu_f(float x) {
    return x / (1.0f + __expf(-x));
}

__device__ __forceinline__ unsigned short f2bf(float x) {
    union { float f; unsigned u; } v; v.f = x;
    unsigned r = v.u + 0x7fffu + ((v.u >> 16) & 1u);
    return (unsigned short)(r >> 16);
}

// ---------------------------------------------------------------------------
// Pack W (10 layer-sets, [160][96] fp32) into MFMA B-fragment bf16 layout.
// ---------------------------------------------------------------------------
__global__ __launch_bounds__(256) void pack_kernel(
    const float* __restrict__ wm, const float* __restrict__ bemb,
    unsigned short* __restrict__ wp, unsigned short* __restrict__ bondbf)
{
    int idx = blockIdx.x * 256 + threadIdx.x;
    if (idx < 10 * FINdim * Hdim) {
        int ls = idx / (FINdim * Hdim), rem = idx % (FINdim * Hdim);
        int k = rem / Hdim, c = rem % Hdim;
        wp[(size_t)ls * FINdim * Hdim + ((size_t)(k >> 3) * Hdim + c) * 8 + (k & 7)] =
            f2bf(wm[idx]);
    } else if (idx < 10 * FINdim * Hdim + 80) {
        int i = idx - 10 * FINdim * Hdim;
        bondbf[i] = f2bf(bemb[i]);
    }
}

// ---------------------------------------------------------------------------
__global__ __launch_bounds__(64) void temb_kernel(
    const float* __restrict__ t, const float* __restrict__ w1, const float* __restrict__ b1,
    const float* __restrict__ w2, const float* __restrict__ b2, float* __restrict__ temb)
{
    int b = blockIdx.x, j = threadIdx.x;
    __shared__ float row[TDdim];
    __shared__ float hid[TDdim];
    row[j] = t[b * TDdim + j];
    __syncthreads();
    float h = b1[j];
    #pragma unroll 8
    for (int i = 0; i < TDdim; ++i) h = fmaf(row[i], w1[i * TDdim + j], h);
    h = silu_f(h);
    hid[j] = h;
    __syncthreads();
    float o = b2[j];
    #pragma unroll 8
    for (int i = 0; i < TDdim; ++i) o = fmaf(hid[i], w2[i * Sdim + j], o);
    temb[b * Sdim + j] = silu_f(o);
}

// ---------------------------------------------------------------------------
__global__ __launch_bounds__(256) void node_init_kernel(
    const int* __restrict__ x, const int* __restrict__ batch,
    const float* __restrict__ aemb, const float* __restrict__ temb,
    float* __restrict__ sfeat, unsigned short* __restrict__ sbf, int n)
{
    int idx = blockIdx.x * 256 + threadIdx.x;
    if (idx >= n * Sdim) return;
    int node = idx >> 6, j = idx & 63;
    int x0 = x[node * 3 + 0], x1 = x[node * 3 + 1], x2 = x[node * 3 + 2];
    float v = aemb[(0 * 16 + x0) * Sdim + j] + aemb[(16 + x1) * Sdim + j]
            + aemb[(32 + x2) * Sdim + j] + temb[batch[node] * Sdim + j];
    sfeat[idx] = v;
    sbf[idx]   = f2bf(v);
}

// ---------------------------------------------------------------------------
// CSR build
// ---------------------------------------------------------------------------
__global__ __launch_bounds__(256) void count_kernel(
    const int* __restrict__ ei, int E, int* __restrict__ counts)
{
    int e = blockIdx.x * 256 + threadIdx.x;
    if (e >= E) return;
    atomicAdd(&counts[ei[E + e]], 1);
}

// single block; parallel scan (wave shuffle-scan + cross-wave offsets)
__global__ __launch_bounds__(256) void scan_kernel(
    const int* __restrict__ counts, int n,
    int* __restrict__ rowStart, int* __restrict__ cursor)
{
    __shared__ int wsum[4];
    int t = threadIdx.x;
    int chunk = n / 256;
    int base = t * chunk;
    int s = 0;
    for (int i = 0; i < chunk; ++i) s += counts[base + i];
    int lane = t & 63, w = t >> 6;
    int sc = s;
    #pragma unroll
    for (int off = 1; off < 64; off <<= 1) {
        int xv = __shfl_up(sc, off);
        if (lane >= off) sc += xv;
    }
    if (lane == 63) wsum[w] = sc;
    __syncthreads();
    int woff = 0;
    for (int i = 0; i < w; ++i) woff += wsum[i];
    int off = woff + sc - s;   // exclusive prefix for this thread's chunk
    for (int i = 0; i < chunk; ++i) {
        rowStart[base + i] = off;
        cursor[base + i]   = off;
        off += counts[base + i];
    }
    if (t == 255) rowStart[n] = off;
}

__global__ __launch_bounds__(256) void scatter_kernel(
    const int* __restrict__ ei, const int* __restrict__ ea, int E,
    int* __restrict__ cursor, int2* __restrict__ st2, int* __restrict__ eaS)
{
    int e = blockIdx.x * 256 + threadIdx.x;
    if (e >= E) return;
    int tgt = ei[E + e];
    int p = atomicAdd(&cursor[tgt], 1);
    st2[p] = make_int2(ei[e], tgt);
    eaS[p] = ea[e];
}

// ---------------------------------------------------------------------------
// One-time per-edge geometry (layer-invariant).
// ---------------------------------------------------------------------------
__global__ __launch_bounds__(256) void geom_kernel(
    const float* __restrict__ pos,
    const int2* __restrict__ st2, const int* __restrict__ eaS,
    const unsigned short* __restrict__ bondbf,
    float4* __restrict__ rn4, unsigned short* __restrict__ rbfb,
    int E, float cutoff)
{
    int e = blockIdx.x * 256 + threadIdx.x;
    if (e >= E) return;
    int2 st = st2[e];
    int s = st.x, t = st.y;
    float rx = pos[3*t]-pos[3*s], ry = pos[3*t+1]-pos[3*s+1], rz = pos[3*t+2]-pos[3*s+2];
    float d = sqrtf(fmaxf(rx*rx + ry*ry + rz*rz, 1e-6f));
    float invd = 1.0f / d;
    rn4[e] = make_float4(rx*invd, ry*invd, rz*invd, d);
    float env = (d < cutoff) ? 0.5f * (__cosf(3.14159265358979f * d / cutoff) + 1.0f) : 0.0f;
    float invw = (float)RDdim / cutoff;
    unsigned int pk[8];
    #pragma unroll
    for (int i2 = 0; i2 < 8; ++i2) {
        float c0 = cutoff * ((float)(2*i2)     / 15.0f);
        float c1 = cutoff * ((float)(2*i2 + 1) / 15.0f);
        float t0 = (d - c0) * invw, t1 = (d - c1) * invw;
        unsigned short b0 = f2bf(__expf(-0.5f * t0 * t0) * env);
        unsigned short b1 = f2bf(__expf(-0.5f * t1 * t1) * env);
        pk[i2] = (unsigned)b0 | ((unsigned)b1 << 16);
    }
    uint4* o = reinterpret_cast<uint4*>(rbfb + (size_t)e * 32);
    o[0] = make_uint4(pk[0], pk[1], pk[2], pk[3]);
    o[1] = make_uint4(pk[4], pk[5], pk[6], pk[7]);
    int ea = eaS[e];
    const uint4* bp = reinterpret_cast<const uint4*>(bondbf + ea * EDdim);
    o[2] = bp[0];
    o[3] = bp[1];
}

// ---------------------------------------------------------------------------
// Fused layer-set kernel: 3 waves/block, 2 col-tiles per wave (B pinned in
// VGPRs), one-chunk software pipeline, zero barriers in the chunk loop, and
// a STREAMING segmented reduce: running sums carried in registers, flushed
// once per node.  Flush rule: BEFORE accumulating edge g0, drain all nodes
// whose segment ends at or before g0 (g0 >= rsEnd) — this handles EMPTY
// NODES correctly (r10 bug: `==` never fired for deg-0 nodes).  A final
// drain after the last chunk flushes the trailing node + trailing empties.
// ---------------------------------------------------------------------------
__global__ __launch_bounds__(192, 4) void fused_layer_tri(
    const float* __restrict__ s_in, float* __restrict__ s_out,
    const unsigned short* __restrict__ sbf_in, unsigned short* __restrict__ sbf_out,
    const float* __restrict__ v_in, float* __restrict__ v_out,
    const int* __restrict__ rowStart,
    const int2* __restrict__ st2,
    const float4* __restrict__ rn4, const unsigned short* __restrict__ rbfb,
    const unsigned short* __restrict__ wp, const float* __restrict__ bg,
    const float* __restrict__ wu, const float* __restrict__ bu,
    const float* __restrict__ lng, const float* __restrict__ lnb,
    int do_ln)
{
    __shared__ float accL[GW * ACCW];               // 3616 B
    __shared__ __align__(16) float hS[16 * HPAD];   // 6272 B
    __shared__ __align__(16) float vS[16 * VSW];    // 3328 B
    __shared__ __align__(16) float rnS[16 * 4];     // 256 B
    __shared__ int rsW[3][GW + 1];

    const int tid  = threadIdx.x;
    const int lane = tid & 63;
    const int wid  = __builtin_amdgcn_readfirstlane(tid >> 6);  // 0,1,2
    const int l15  = lane & 15, l4 = lane >> 4;
    const int n0   = blockIdx.x * GW;
    const int colm = wid * 32 + (lane & 31);        // mirrored col (wid<2)

    // ---- B fragments: 2 col tiles per wave; pinned resident ----
    bf16x8 B0[5], B1[5];
    #pragma unroll
    for (int kk = 0; kk < 5; ++kk) {
        B0[kk] = *reinterpret_cast<const bf16x8*>(
            wp + ((size_t)(kk * 4 + l4) * Hdim + (wid * 2 + 0) * 16 + l15) * 8);
        B1[kk] = *reinterpret_cast<const bf16x8*>(
            wp + ((size_t)(kk * 4 + l4) * Hdim + (wid * 2 + 1) * 16 + l15) * 8);
    }
    #pragma unroll
    for (int kk = 0; kk < 5; ++kk)
        asm volatile("" : "+v"(B0[kk]), "+v"(B1[kk]));   // forbid remat into loop
    const float bias0 = bg[(wid * 2 + 0) * 16 + l15];
    const float bias1 = bg[(wid * 2 + 1) * 16 + l15];

    // ---- per-wave rowStart copy in LDS (in-wave ordering => no barrier) ----
    if (lane <= GW) rsW[wid][lane] = rowStart[n0 + lane];

    const int eW0 = __builtin_amdgcn_readfirstlane(rsW[wid][0]);
    const int eW1 = __builtin_amdgcn_readfirstlane(rsW[wid][GW]);

    // ---- streaming reduce state (carried across the whole edge range) ----
    float msum = 0.0f, vsum = 0.0f;
    int   ni    = 0;
    int   rsEnd = __builtin_amdgcn_readfirstlane(rsW[wid][1]);

    auto flushNode = [&]() {
        if (wid < 2)           accL[ni * ACCW + colm]      = msum;
        else if (lane < NVdim) accL[ni * ACCW + 64 + lane] = vsum;
        msum = 0.0f; vsum = 0.0f;
        ++ni;
        rsEnd = (ni < GW)
            ? __builtin_amdgcn_readfirstlane(rsW[wid][ni + 1])
            : 0x7fffffff;
    };

    auto reducePrev = [&](int pb) {
        const int pv = min(16, eW1 - pb);
        for (int e2 = 0; e2 < pv; ++e2) {
            const int g0 = pb + e2;                 // this edge's global index
            while (ni < GW && g0 >= rsEnd) flushNode();  // drain finished/empty nodes
            if (wid < 2) {
                msum += hS[e2 * HPAD + colm];
            } else if (lane < NVdim) {
                vsum += vS[e2 * VSW + lane] * hS[e2 * HPAD + 64 + l15]
                      + rnS[e2 * 4 + l4]    * hS[e2 * HPAD + 80 + l15];
            }
        }
    };

    // ---- pipeline prologue: indices for chunk 0 (unclamped; st2 padded) ----
    int2 stM = st2[eW0 + l15];
    int  sSt = 0;
    if (wid == 2) sSt = st2[eW0 + (lane >> 2)].x;
    int prevBase = -1;

    for (int base = eW0; base < eW1; base += 16) {
        // 1. A-fragment gathers for current chunk (issue early)
        const unsigned short* sp = sbf_in + (size_t)stM.x * Sdim;
        const unsigned short* tp = sbf_in + (size_t)stM.y * Sdim;
        bf16x8 a0 = *reinterpret_cast<const bf16x8*>(sp + l4 * 8);
        bf16x8 a1 = *reinterpret_cast<const bf16x8*>(sp + 32 + l4 * 8);
        bf16x8 a2 = *reinterpret_cast<const bf16x8*>(tp + l4 * 8);
        bf16x8 a3 = *reinterpret_cast<const bf16x8*>(tp + 32 + l4 * 8);
        bf16x8 a4 = *reinterpret_cast<const bf16x8*>(
            rbfb + (size_t)(base + l15) * 32 + l4 * 8);

        // 2. next-chunk index prefetch + v/rn gathers
        int2 stMn = st2[base + 16 + l15];
        int  sStn = 0;
        float4 va, vb, vc, rnv;
        if (wid == 2) {
            sStn = st2[base + 16 + (lane >> 2)].x;
            const int q = lane & 3;
            const float* vp = v_in + (size_t)sSt * NVdim + q * 12;
            va = *reinterpret_cast<const float4*>(vp);
            vb = *reinterpret_cast<const float4*>(vp + 4);
            vc = *reinterpret_cast<const float4*>(vp + 8);
            if (lane < 16) rnv = rn4[base + lane];
        }

        // 3. streaming reduce of previous chunk (covers load latency above)
        if (prevBase >= 0) reducePrev(prevBase);

        // 4. MFMA: 16 edges x 32 cols x K=160
        f32x4 c0 = (f32x4){0.f, 0.f, 0.f, 0.f};
        f32x4 c1 = (f32x4){0.f, 0.f, 0.f, 0.f};
        c0 = __builtin_amdgcn_mfma_f32_16x16x32_bf16(a0, B0[0], c0, 0, 0, 0);
        c1 = __builtin_amdgcn_mfma_f32_16x16x32_bf16(a0, B1[0], c1, 0, 0, 0);
        c0 = __builtin_amdgcn_mfma_f32_16x16x32_bf16(a1, B0[1], c0, 0, 0, 0);
        c1 = __builtin_amdgcn_mfma_f32_16x16x32_bf16(a1, B1[1], c1, 0, 0, 0);
        c0 = __builtin_amdgcn_mfma_f32_16x16x32_bf16(a2, B0[2], c0, 0, 0, 0);
        c1 = __builtin_amdgcn_mfma_f32_16x16x32_bf16(a2, B1[2], c1, 0, 0, 0);
        c0 = __builtin_amdgcn_mfma_f32_16x16x32_bf16(a3, B0[3], c0, 0, 0, 0);
        c1 = __builtin_amdgcn_mfma_f32_16x16x32_bf16(a3, B1[3], c1, 0, 0, 0);
        c0 = __builtin_amdgcn_mfma_f32_16x16x32_bf16(a4, B0[4], c0, 0, 0, 0);
        c1 = __builtin_amdgcn_mfma_f32_16x16x32_bf16(a4, B1[4], c1, 0, 0, 0);

        // 5. epilogue: bias + silu -> own hS columns
        #pragma unroll
        for (int r = 0; r < 4; ++r) {
            hS[(l4 * 4 + r) * HPAD + wid * 32 + l15]      = silu_f(c0[r] + bias0);
            hS[(l4 * 4 + r) * HPAD + wid * 32 + 16 + l15] = silu_f(c1[r] + bias1);
        }
        // 6. commit staging for this chunk (read by reduce next iteration)
        if (wid == 2) {
            const int el = lane >> 2, q = lane & 3;
            *reinterpret_cast<float4*>(&vS[el * VSW + q * 12 + 0]) = va;
            *reinterpret_cast<float4*>(&vS[el * VSW + q * 12 + 4]) = vb;
            *reinterpret_cast<float4*>(&vS[el * VSW + q * 12 + 8]) = vc;
            if (lane < 16) *reinterpret_cast<float4*>(&rnS[lane * 4]) = rnv;
        }
        prevBase = base;
        stM = stMn; sSt = sStn;
    }
    if (prevBase >= 0) reducePrev(prevBase);
    // final drain: flush the trailing node's carried sums + trailing empties
    while (ni < GW) flushNode();
    __syncthreads();

    // ---- node update: wave w handles nodes w, w+3, ... ----
    for (int i = wid; i < GW; i += 3) {
        const int node = n0 + i;
        const float cntn = (float)(rsW[wid][i + 1] - rsW[wid][i]);
        const float ic = 1.0f / fmaxf(cntn, 1.0f);
        const float* al = &accL[i * ACCW];
        float dot = 0.0f;
        #pragma unroll 8
        for (int ii = 0; ii < Sdim; ++ii) dot = fmaf(al[ii], wu[ii * Sdim + lane], dot);
        float sn = s_in[(size_t)node * Sdim + lane] + silu_f(fmaf(dot, ic, bu[lane]));
        if (do_ln) {
            float mm = sn;
            #pragma unroll
            for (int off = 32; off >= 1; off >>= 1) mm += __shfl_xor(mm, off);
            mm *= (1.0f / 64.0f);
            float dv = sn - mm;
            float var = dv * dv;
            #pragma unroll
            for (int off = 32; off >= 1; off >>= 1) var += __shfl_xor(var, off);
            var *= (1.0f / 64.0f);
            sn = dv * rsqrtf(var + 1e-5f) * lng[lane] + lnb[lane];
        }
        s_out[(size_t)node * Sdim + lane]   = sn;
        sbf_out[(size_t)node * Sdim + lane] = f2bf(sn);
        if (lane < NVdim)
            v_out[(size_t)node * NVdim + lane] =
                v_in[(size_t)node * NVdim + lane] + accL[i * ACCW + Sdim + lane] * ic;
    }
}

// ---------------------------------------------------------------------------
// Head
// ---------------------------------------------------------------------------
__global__ __launch_bounds__(64) void head1_kernel(
    const float* __restrict__ sfeat, const float* __restrict__ vfeat,
    const float* __restrict__ wd, const float* __restrict__ wo,
    float* __restrict__ dsc, float* __restrict__ out)
{
    int node = blockIdx.x, j = threadIdx.x;
    float val = silu_f(sfeat[(size_t)node * Sdim + j]) * wd[j];
    #pragma unroll
    for (int off = 32; off >= 1; off >>= 1) val += __shfl_xor(val, off);
    if (j == 0) dsc[node] = val;
    if (j < 3) {
        float a = 0.0f;
        #pragma unroll
        for (int m = 0; m < Vdim; ++m)
            a += vfeat[(size_t)node * NVdim + j * Vdim + m] * wo[m];
        out[(size_t)node * 3 + j] = a;
    }
}

// node-parallel over CSR-G; no atomics.  pos[src]-pos[tgt] = -rn.xyz * d.
__global__ __launch_bounds__(256) void head2_kernel(
    const float* __restrict__ dsc, const int* __restrict__ rsG,
    const int2* __restrict__ st2G, const float4* __restrict__ rn4G,
    float* __restrict__ out, int n)
{
    int t = blockIdx.x * 256 + threadIdx.x;
    if (t >= n) return;
    int lo = rsG[t], hi = rsG[t + 1];
    float dt = dsc[t];
    float ax = 0.f, ay = 0.f, az = 0.f;
    for (int e = lo; e < hi; ++e) {
        float w = dsc[st2G[e].x] + dt;
        float4 rn = rn4G[e];
        float wd_ = w * rn.w;
        ax -= wd_ * rn.x; ay -= wd_ * rn.y; az -= wd_ * rn.z;
    }
    out[3 * t + 0] += ax;
    out[3 * t + 1] += ay;
    out[3 * t + 2] += az;
}

// ---------------------------------------------------------------------------
extern "C" void kernel_launch(void* const* d_in, const int* in_sizes, int n_in,
                              void* d_out, int out_size, void* d_ws, size_t ws_size,
                              hipStream_t stream)
{
    const int*   x     = (const int*)d_in[0];
    const float* t     = (const float*)d_in[1];
    const float* pos   = (const float*)d_in[2];
    const int*   eil   = (const int*)d_in[3];
    const int*   eig   = (const int*)d_in[4];
    const int*   eal   = (const int*)d_in[5];
    const int*   eag   = (const int*)d_in[6];
    const int*   batch = (const int*)d_in[7];
    const float* aemb  = (const float*)d_in[8];
    const float* bemb  = (const float*)d_in[9];
    const float* t_w1  = (const float*)d_in[10];
    const float* t_b1  = (const float*)d_in[11];
    const float* t_w2  = (const float*)d_in[12];
    const float* t_b2  = (const float*)d_in[13];
    const float* wm    = (const float*)d_in[14];
    const float* bm    = (const float*)d_in[15];
    const float* wu    = (const float*)d_in[16];
    const float* bu    = (const float*)d_in[17];
    const float* lng   = (const float*)d_in[18];
    const float* lnb   = (const float*)d_in[19];
    const float* wd    = (const float*)d_in[20];
    const float* wo    = (const float*)d_in[21];

    const int n  = in_sizes[7];          // 16384
    const int B  = in_sizes[1] / TDdim;  // 64
    const int EL = in_sizes[3] / 2;      // 131072
    const int EG = in_sizes[4] / 2;      // 262144
    const int PAD = 32;                  // gather overrun pad (entries)

    // ---- workspace layout ----
    char* p = (char*)d_ws;
    auto alignup = [](char* q) { return (char*)(((size_t)q + 15) & ~(size_t)15); };

    float* temb = (float*)p;                 p += (size_t)B * Sdim * 4;
    float* dsc  = (float*)p;                 p += (size_t)n * 4;
    float* sA   = (float*)p;                 p += (size_t)n * Sdim * 4;
    float* sB   = (float*)p;                 p += (size_t)n * Sdim * 4;
    float* vA   = (float*)p;                 p += (size_t)n * NVdim * 4;
    float* vB   = (float*)p;                 p += (size_t)n * NVdim * 4;
    int* counts = (int*)p;                   p += (size_t)n * 4;
    int* cursor = (int*)p;                   p += (size_t)n * 4;
    int* rsL    = (int*)p;                   p += (size_t)(n + 4) * 4;
    int* rsG    = (int*)p;                   p += (size_t)(n + 4) * 4;
    int* eaL2   = (int*)p;                   p += (size_t)EL * 4;
    int* eaG2   = (int*)p;                   p += (size_t)EG * 4;
    p = alignup(p);
    int2* st2L  = (int2*)p;                  p += (size_t)(EL + PAD) * 8;
    int2* st2G  = (int2*)p;                  p += (size_t)(EG + PAD) * 8;
    p = alignup(p);
    unsigned short* wp     = (unsigned short*)p;  p += (size_t)10 * FINdim * Hdim * 2;
    p = alignup(p);
    unsigned short* bondbf = (unsigned short*)p;  p += 96 * 2;
    p = alignup(p);
    unsigned short* sbfA   = (unsigned short*)p;  p += (size_t)n * Sdim * 2;
    unsigned short* sbfB   = (unsigned short*)p;  p += (size_t)n * Sdim * 2;
    p = alignup(p);
    float4* rn4L = (float4*)p;               p += (size_t)(EL + PAD) * 16;
    float4* rn4G = (float4*)p;               p += (size_t)(EG + PAD) * 16;
    unsigned short* rbfbL = (unsigned short*)p;  p += (size_t)(EL + PAD) * 32 * 2;
    unsigned short* rbfbG = (unsigned short*)p;  p += (size_t)(EG + PAD) * 32 * 2;

    float* out = (float*)d_out;

    // ---- precompute packed weights + init ----
    pack_kernel<<<(10 * FINdim * Hdim + 80 + 255) / 256, 256, 0, stream>>>(wm, bemb, wp, bondbf);
    temb_kernel<<<B, 64, 0, stream>>>(t, t_w1, t_b1, t_w2, t_b2, temb);
    node_init_kernel<<<(n * Sdim + 255) / 256, 256, 0, stream>>>(x, batch, aemb, temb, sA, sbfA, n);
    hipMemsetAsync(vA, 0, (size_t)n * NVdim * sizeof(float), stream);
    // zero the st2 pads (indices must be safe: node 0)
    hipMemsetAsync(st2L + EL, 0, PAD * sizeof(int2), stream);
    hipMemsetAsync(st2G + EG, 0, PAD * sizeof(int2), stream);

    // ---- CSR build ----
    hipMemsetAsync(counts, 0, (size_t)n * sizeof(int), stream);
    count_kernel<<<(EL + 255) / 256, 256, 0, stream>>>(eil, EL, counts);
    scan_kernel<<<1, 256, 0, stream>>>(counts, n, rsL, cursor);
    scatter_kernel<<<(EL + 255) / 256, 256, 0, stream>>>(eil, eal, EL, cursor, st2L, eaL2);

    hipMemsetAsync(counts, 0, (size_t)n * sizeof(int), stream);
    count_kernel<<<(EG + 255) / 256, 256, 0, stream>>>(eig, EG, counts);
    scan_kernel<<<1, 256, 0, stream>>>(counts, n, rsG, cursor);
    scatter_kernel<<<(EG + 255) / 256, 256, 0, stream>>>(eig, eag, EG, cursor, st2G, eaG2);

    // ---- one-time edge geometry (layer-invariant) ----
    geom_kernel<<<(EL + 255) / 256, 256, 0, stream>>>(pos, st2L, eaL2, bondbf, rn4L, rbfbL, EL, 3.0f);
    geom_kernel<<<(EG + 255) / 256, 256, 0, stream>>>(pos, st2G, eaG2, bondbf, rn4G, rbfbG, EG, 10.0f);

    // ---- layers ----
    float* s_cur = sA; float* s_nxt = sB;
    float* v_cur = vA; float* v_nxt = vB;
    unsigned short* sb_cur = sbfA; unsigned short* sb_nxt = sbfB;

    for (int l = 0; l < NLAYER; ++l) {
        for (int k = 0; k < 2; ++k) {
            int ls = l * 2 + k;
            const unsigned short* wpk = wp + (size_t)ls * FINdim * Hdim;
            const float* bgk = bm + (size_t)ls * Hdim;
            const float* wuk = wu + (size_t)ls * Sdim * Sdim;
            const float* buk = bu + (size_t)ls * Sdim;
            if (k == 0) {
                fused_layer_tri<<<n / GW, 192, 0, stream>>>(
                    s_cur, s_nxt, sb_cur, sb_nxt, v_cur, v_nxt,
                    rsL, st2L, rn4L, rbfbL, wpk, bgk, wuk, buk,
                    lng + (size_t)l * Sdim, lnb + (size_t)l * Sdim, 0);
            } else {
                fused_layer_tri<<<n / GW, 192, 0, stream>>>(
                    s_cur, s_nxt, sb_cur, sb_nxt, v_cur, v_nxt,
                    rsG, st2G, rn4G, rbfbG, wpk, bgk, wuk, buk,
                    lng + (size_t)l * Sdim, lnb + (size_t)l * Sdim, 1);
            }
            float* tmp = s_cur; s_cur = s_nxt; s_nxt = tmp;
            tmp = v_cur; v_cur = v_nxt; v_nxt = tmp;
            unsigned short* tb = sb_cur; sb_cur = sb_nxt; sb_nxt = tb;
        }
    }

    head1_kernel<<<n, 64, 0, stream>>>(s_cur, v_cur, wd, wo, dsc, out);
    head2_kernel<<<(n + 255) / 256, 256, 0, stream>>>(dsc, rsG, st2G, rn4G, out, n);
}

// Round 12
// 685.963 us; speedup vs baseline: 1.1678x; 1.1678x over previous
//
#include <hip/hip_runtime.h>
#include <math.h>

#define Sdim 64
#define Vdim 16
#define NLAYER 5
#define EDdim 16
#define RDdim 16
#define TDdim 64
#define FINdim 160   // 2*S + RD + ED
#define Hdim 96      // S + 2*V
#define NVdim 48     // 3*V

typedef __attribute__((ext_vector_type(8))) short bf16x8;
typedef __attribute__((ext_vector_type(4))) float f32x4;

__device__ __forceinline__ float silu_f(float x) {
    return x / (1.0f + __expf(-x));
}

__device__ __forceinline__ unsigned short f2bf(float x) {
    union { float f; unsigned u; } v; v.f = x;
    unsigned r = v.u + 0x7fffu + ((v.u >> 16) & 1u);
    return (unsigned short)(r >> 16);
}

__device__ __forceinline__ float bf2f(unsigned short u) {
    union { unsigned u; float f; } v; v.u = (unsigned)u << 16;
    return v.f;
}

// ---------------------------------------------------------------------------
// Pack W (10 layer-sets, [160][96] fp32) into MFMA B-fragment bf16 layout.
// ---------------------------------------------------------------------------
__global__ __launch_bounds__(256) void pack_kernel(
    const float* __restrict__ wm, const float* __restrict__ bemb,
    unsigned short* __restrict__ wp, unsigned short* __restrict__ bondbf)
{
    int idx = blockIdx.x * 256 + threadIdx.x;
    if (idx < 10 * FINdim * Hdim) {
        int ls = idx / (FINdim * Hdim), rem = idx % (FINdim * Hdim);
        int k = rem / Hdim, c = rem % Hdim;
        wp[(size_t)ls * FINdim * Hdim + ((size_t)(k >> 3) * Hdim + c) * 8 + (k & 7)] =
            f2bf(wm[idx]);
    } else if (idx < 10 * FINdim * Hdim + 80) {
        int i = idx - 10 * FINdim * Hdim;
        bondbf[i] = f2bf(bemb[i]);
    }
}

// ---------------------------------------------------------------------------
__global__ __launch_bounds__(64) void temb_kernel(
    const float* __restrict__ t, const float* __restrict__ w1, const float* __restrict__ b1,
    const float* __restrict__ w2, const float* __restrict__ b2, float* __restrict__ temb)
{
    int b = blockIdx.x, j = threadIdx.x;
    __shared__ float row[TDdim];
    __shared__ float hid[TDdim];
    row[j] = t[b * TDdim + j];
    __syncthreads();
    float h = b1[j];
    #pragma unroll 8
    for (int i = 0; i < TDdim; ++i) h = fmaf(row[i], w1[i * TDdim + j], h);
    h = silu_f(h);
    hid[j] = h;
    __syncthreads();
    float o = b2[j];
    #pragma unroll 8
    for (int i = 0; i < TDdim; ++i) o = fmaf(hid[i], w2[i * Sdim + j], o);
    temb[b * Sdim + j] = silu_f(o);
}

// ---------------------------------------------------------------------------
__global__ __launch_bounds__(256) void node_init_kernel(
    const int* __restrict__ x, const int* __restrict__ batch,
    const float* __restrict__ aemb, const float* __restrict__ temb,
    float* __restrict__ sfeat, unsigned short* __restrict__ sbf, int n)
{
    int idx = blockIdx.x * 256 + threadIdx.x;
    if (idx >= n * Sdim) return;
    int node = idx >> 6, j = idx & 63;
    int x0 = x[node * 3 + 0], x1 = x[node * 3 + 1], x2 = x[node * 3 + 2];
    float v = aemb[(0 * 16 + x0) * Sdim + j] + aemb[(16 + x1) * Sdim + j]
            + aemb[(32 + x2) * Sdim + j] + temb[batch[node] * Sdim + j];
    sfeat[idx] = v;
    sbf[idx]   = f2bf(v);
}

// ---------------------------------------------------------------------------
// CSR build
// ---------------------------------------------------------------------------
__global__ __launch_bounds__(256) void count_kernel(
    const int* __restrict__ ei, int E, int* __restrict__ counts)
{
    int e = blockIdx.x * 256 + threadIdx.x;
    if (e >= E) return;
    atomicAdd(&counts[ei[E + e]], 1);
}

// single block; parallel scan (wave shuffle-scan + cross-wave offsets)
__global__ __launch_bounds__(256) void scan_kernel(
    const int* __restrict__ counts, int n,
    int* __restrict__ rowStart, int* __restrict__ cursor)
{
    __shared__ int wsum[4];
    int t = threadIdx.x;
    int chunk = n / 256;
    int base = t * chunk;
    int s = 0;
    for (int i = 0; i < chunk; ++i) s += counts[base + i];
    int lane = t & 63, w = t >> 6;
    int sc = s;
    #pragma unroll
    for (int off = 1; off < 64; off <<= 1) {
        int xv = __shfl_up(sc, off);
        if (lane >= off) sc += xv;
    }
    if (lane == 63) wsum[w] = sc;
    __syncthreads();
    int woff = 0;
    for (int i = 0; i < w; ++i) woff += wsum[i];
    int off = woff + sc - s;   // exclusive prefix for this thread's chunk
    for (int i = 0; i < chunk; ++i) {
        rowStart[base + i] = off;
        cursor[base + i]   = off;
        off += counts[base + i];
    }
    if (t == 255) rowStart[n] = off;
}

__global__ __launch_bounds__(256) void scatter_kernel(
    const int* __restrict__ ei, const int* __restrict__ ea, int E,
    int* __restrict__ cursor, int2* __restrict__ st2, int* __restrict__ eaS)
{
    int e = blockIdx.x * 256 + threadIdx.x;
    if (e >= E) return;
    int tgt = ei[E + e];
    int p = atomicAdd(&cursor[tgt], 1);
    st2[p] = make_int2(ei[e], tgt);
    eaS[p] = ea[e];
}

// ---------------------------------------------------------------------------
// One-time per-edge geometry (layer-invariant).
// ---------------------------------------------------------------------------
__global__ __launch_bounds__(256) void geom_kernel(
    const float* __restrict__ pos,
    const int2* __restrict__ st2, const int* __restrict__ eaS,
    const unsigned short* __restrict__ bondbf,
    float4* __restrict__ rn4, unsigned short* __restrict__ rbfb,
    int E, float cutoff)
{
    int e = blockIdx.x * 256 + threadIdx.x;
    if (e >= E) return;
    int2 st = st2[e];
    int s = st.x, t = st.y;
    float rx = pos[3*t]-pos[3*s], ry = pos[3*t+1]-pos[3*s+1], rz = pos[3*t+2]-pos[3*s+2];
    float d = sqrtf(fmaxf(rx*rx + ry*ry + rz*rz, 1e-6f));
    float invd = 1.0f / d;
    rn4[e] = make_float4(rx*invd, ry*invd, rz*invd, d);
    float env = (d < cutoff) ? 0.5f * (__cosf(3.14159265358979f * d / cutoff) + 1.0f) : 0.0f;
    float invw = (float)RDdim / cutoff;
    unsigned int pk[8];
    #pragma unroll
    for (int i2 = 0; i2 < 8; ++i2) {
        float c0 = cutoff * ((float)(2*i2)     / 15.0f);
        float c1 = cutoff * ((float)(2*i2 + 1) / 15.0f);
        float t0 = (d - c0) * invw, t1 = (d - c1) * invw;
        unsigned short b0 = f2bf(__expf(-0.5f * t0 * t0) * env);
        unsigned short b1 = f2bf(__expf(-0.5f * t1 * t1) * env);
        pk[i2] = (unsigned)b0 | ((unsigned)b1 << 16);
    }
    uint4* o = reinterpret_cast<uint4*>(rbfb + (size_t)e * 32);
    o[0] = make_uint4(pk[0], pk[1], pk[2], pk[3]);
    o[1] = make_uint4(pk[4], pk[5], pk[6], pk[7]);
    int ea = eaS[e];
    const uint4* bp = reinterpret_cast<const uint4*>(bondbf + ea * EDdim);
    o[2] = bp[0];
    o[3] = bp[1];
}

// ---------------------------------------------------------------------------
// Kernel A: edge MLP as a pure tall-skinny GEMM.  256 threads = 4 waves,
// each wave owns TWO independent 16-edge stripes (128 edges/block).
// W staged in LDS once; B-fragments ds_read per (kk,nt), shared by both
// stripes.  No loops, no reduce, no post-staging barriers — latency hidden
// by occupancy.  Outputs: hm[E][64] (ms part), hv[E][32] (wv part), bf16.
// ---------------------------------------------------------------------------
__global__ __launch_bounds__(256) void edge_mlp_kernel(
    const unsigned short* __restrict__ sbf_in,
    const int2* __restrict__ st2,
    const unsigned short* __restrict__ rbfb,
    const unsigned short* __restrict__ wpk,
    const float* __restrict__ bg,
    unsigned short* __restrict__ hm,
    unsigned short* __restrict__ hv)
{
    __shared__ __align__(16) unsigned short Wl[FINdim * Hdim];  // 30720 B
    {
        const uint4* s4 = reinterpret_cast<const uint4*>(wpk);
        uint4* d4 = reinterpret_cast<uint4*>(Wl);
        for (int i = threadIdx.x; i < FINdim * Hdim / 8; i += 256) d4[i] = s4[i];
    }
    __syncthreads();

    const int lane = threadIdx.x & 63;
    const int wid  = threadIdx.x >> 6;
    const int l15 = lane & 15, l4 = lane >> 4;
    const int base0 = blockIdx.x * 128 + wid * 16;
    const int base1 = base0 + 64;

    const int2 st0 = st2[base0 + l15];
    const int2 st1 = st2[base1 + l15];
    bf16x8 a0[5], a1[5];
    {
        const unsigned short* sp = sbf_in + (size_t)st0.x * Sdim;
        const unsigned short* tp = sbf_in + (size_t)st0.y * Sdim;
        a0[0] = *reinterpret_cast<const bf16x8*>(sp + l4 * 8);
        a0[1] = *reinterpret_cast<const bf16x8*>(sp + 32 + l4 * 8);
        a0[2] = *reinterpret_cast<const bf16x8*>(tp + l4 * 8);
        a0[3] = *reinterpret_cast<const bf16x8*>(tp + 32 + l4 * 8);
        a0[4] = *reinterpret_cast<const bf16x8*>(rbfb + (size_t)(base0 + l15) * 32 + l4 * 8);
    }
    {
        const unsigned short* sp = sbf_in + (size_t)st1.x * Sdim;
        const unsigned short* tp = sbf_in + (size_t)st1.y * Sdim;
        a1[0] = *reinterpret_cast<const bf16x8*>(sp + l4 * 8);
        a1[1] = *reinterpret_cast<const bf16x8*>(sp + 32 + l4 * 8);
        a1[2] = *reinterpret_cast<const bf16x8*>(tp + l4 * 8);
        a1[3] = *reinterpret_cast<const bf16x8*>(tp + 32 + l4 * 8);
        a1[4] = *reinterpret_cast<const bf16x8*>(rbfb + (size_t)(base1 + l15) * 32 + l4 * 8);
    }

    f32x4 acc0[6], acc1[6];
    #pragma unroll
    for (int nt = 0; nt < 6; ++nt) {
        acc0[nt] = (f32x4){0.f, 0.f, 0.f, 0.f};
        acc1[nt] = (f32x4){0.f, 0.f, 0.f, 0.f};
    }
    #pragma unroll
    for (int kk = 0; kk < 5; ++kk) {
        #pragma unroll
        for (int nt = 0; nt < 6; ++nt) {
            bf16x8 b = *reinterpret_cast<const bf16x8*>(
                Wl + ((size_t)(kk * 4 + l4) * Hdim + nt * 16 + l15) * 8);
            acc0[nt] = __builtin_amdgcn_mfma_f32_16x16x32_bf16(a0[kk], b, acc0[nt], 0, 0, 0);
            acc1[nt] = __builtin_amdgcn_mfma_f32_16x16x32_bf16(a1[kk], b, acc1[nt], 0, 0, 0);
        }
    }

    // epilogue: bias + silu -> hm/hv (bf16).  D-layout: row = l4*4+r, col = nt*16+l15.
    #pragma unroll
    for (int nt = 0; nt < 6; ++nt) {
        const float bs = bg[nt * 16 + l15];
        #pragma unroll
        for (int r = 0; r < 4; ++r) {
            const int e0 = base0 + l4 * 4 + r;
            const int e1 = base1 + l4 * 4 + r;
            const unsigned short h0 = f2bf(silu_f(acc0[nt][r] + bs));
            const unsigned short h1 = f2bf(silu_f(acc1[nt][r] + bs));
            if (nt < 4) {
                hm[(size_t)e0 * 64 + nt * 16 + l15] = h0;
                hm[(size_t)e1 * 64 + nt * 16 + l15] = h1;
            } else {
                hv[(size_t)e0 * 32 + (nt - 4) * 16 + l15] = h0;
                hv[(size_t)e1 * 32 + (nt - 4) * 16 + l15] = h1;
            }
        }
    }
}

// ---------------------------------------------------------------------------
// Kernel B: segment-mean aggregation + node update.  ONE WAVE PER NODE
// (grid = n), sums carried in registers, CSR rows read streaming.
// ---------------------------------------------------------------------------
__global__ __launch_bounds__(64) void node_agg_kernel(
    const float* __restrict__ s_in, float* __restrict__ s_out,
    unsigned short* __restrict__ sbf_out,
    const float* __restrict__ v_in, float* __restrict__ v_out,
    const int* __restrict__ rowStart, const int2* __restrict__ st2,
    const float* __restrict__ rn4f,
    const unsigned short* __restrict__ hm, const unsigned short* __restrict__ hv,
    const float* __restrict__ wu, const float* __restrict__ bu,
    const float* __restrict__ lng, const float* __restrict__ lnb,
    int do_ln)
{
    const int node = blockIdx.x;
    const int lane = threadIdx.x;
    const int l15 = lane & 15, dd = lane >> 4;
    const int lo = rowStart[node], hi = rowStart[node + 1];

    float msum = 0.0f, vsum = 0.0f;
    for (int e = lo; e < hi; ++e) {
        msum += bf2f(hm[(size_t)e * 64 + lane]);
        if (lane < NVdim) {
            float wv1 = bf2f(hv[(size_t)e * 32 + l15]);
            float wv2 = bf2f(hv[(size_t)e * 32 + 16 + l15]);
            float rnd = rn4f[(size_t)e * 4 + dd];
            int srcN  = st2[e].x;                       // wave-uniform -> scalar
            float vv  = v_in[(size_t)srcN * NVdim + lane];
            vsum = fmaf(vv, wv1, fmaf(rnd, wv2, vsum));
        }
    }

    __shared__ float ag[64];
    const float ic = 1.0f / fmaxf((float)(hi - lo), 1.0f);
    ag[lane] = msum * ic;            // single wave: in-order LDS, no barrier

    float dot = 0.0f;
    #pragma unroll 8
    for (int i = 0; i < Sdim; ++i) dot = fmaf(ag[i], wu[i * Sdim + lane], dot);
    float sn = s_in[(size_t)node * Sdim + lane] + silu_f(dot + bu[lane]);
    if (do_ln) {
        float mm = sn;
        #pragma unroll
        for (int off = 32; off >= 1; off >>= 1) mm += __shfl_xor(mm, off);
        mm *= (1.0f / 64.0f);
        float dv = sn - mm;
        float var = dv * dv;
        #pragma unroll
        for (int off = 32; off >= 1; off >>= 1) var += __shfl_xor(var, off);
        var *= (1.0f / 64.0f);
        sn = dv * rsqrtf(var + 1e-5f) * lng[lane] + lnb[lane];
    }
    s_out[(size_t)node * Sdim + lane]   = sn;
    sbf_out[(size_t)node * Sdim + lane] = f2bf(sn);
    if (lane < NVdim)
        v_out[(size_t)node * NVdim + lane] =
            v_in[(size_t)node * NVdim + lane] + vsum * ic;
}

// ---------------------------------------------------------------------------
// Head
// ---------------------------------------------------------------------------
__global__ __launch_bounds__(64) void head1_kernel(
    const float* __restrict__ sfeat, const float* __restrict__ vfeat,
    const float* __restrict__ wd, const float* __restrict__ wo,
    float* __restrict__ dsc, float* __restrict__ out)
{
    int node = blockIdx.x, j = threadIdx.x;
    float val = silu_f(sfeat[(size_t)node * Sdim + j]) * wd[j];
    #pragma unroll
    for (int off = 32; off >= 1; off >>= 1) val += __shfl_xor(val, off);
    if (j == 0) dsc[node] = val;
    if (j < 3) {
        float a = 0.0f;
        #pragma unroll
        for (int m = 0; m < Vdim; ++m)
            a += vfeat[(size_t)node * NVdim + j * Vdim + m] * wo[m];
        out[(size_t)node * 3 + j] = a;
    }
}

// node-parallel over CSR-G; no atomics.  pos[src]-pos[tgt] = -rn.xyz * d.
__global__ __launch_bounds__(256) void head2_kernel(
    const float* __restrict__ dsc, const int* __restrict__ rsG,
    const int2* __restrict__ st2G, const float4* __restrict__ rn4G,
    float* __restrict__ out, int n)
{
    int t = blockIdx.x * 256 + threadIdx.x;
    if (t >= n) return;
    int lo = rsG[t], hi = rsG[t + 1];
    float dt = dsc[t];
    float ax = 0.f, ay = 0.f, az = 0.f;
    for (int e = lo; e < hi; ++e) {
        float w = dsc[st2G[e].x] + dt;
        float4 rn = rn4G[e];
        float wd_ = w * rn.w;
        ax -= wd_ * rn.x; ay -= wd_ * rn.y; az -= wd_ * rn.z;
    }
    out[3 * t + 0] += ax;
    out[3 * t + 1] += ay;
    out[3 * t + 2] += az;
}

// ---------------------------------------------------------------------------
extern "C" void kernel_launch(void* const* d_in, const int* in_sizes, int n_in,
                              void* d_out, int out_size, void* d_ws, size_t ws_size,
                              hipStream_t stream)
{
    const int*   x     = (const int*)d_in[0];
    const float* t     = (const float*)d_in[1];
    const float* pos   = (const float*)d_in[2];
    const int*   eil   = (const int*)d_in[3];
    const int*   eig   = (const int*)d_in[4];
    const int*   eal   = (const int*)d_in[5];
    const int*   eag   = (const int*)d_in[6];
    const int*   batch = (const int*)d_in[7];
    const float* aemb  = (const float*)d_in[8];
    const float* bemb  = (const float*)d_in[9];
    const float* t_w1  = (const float*)d_in[10];
    const float* t_b1  = (const float*)d_in[11];
    const float* t_w2  = (const float*)d_in[12];
    const float* t_b2  = (const float*)d_in[13];
    const float* wm    = (const float*)d_in[14];
    const float* bm    = (const float*)d_in[15];
    const float* wu    = (const float*)d_in[16];
    const float* bu    = (const float*)d_in[17];
    const float* lng   = (const float*)d_in[18];
    const float* lnb   = (const float*)d_in[19];
    const float* wd    = (const float*)d_in[20];
    const float* wo    = (const float*)d_in[21];

    const int n  = in_sizes[7];          // 16384
    const int B  = in_sizes[1] / TDdim;  // 64
    const int EL = in_sizes[3] / 2;      // 131072
    const int EG = in_sizes[4] / 2;      // 262144

    // ---- workspace layout ----
    char* p = (char*)d_ws;
    auto alignup = [](char* q) { return (char*)(((size_t)q + 15) & ~(size_t)15); };

    float* temb = (float*)p;                 p += (size_t)B * Sdim * 4;
    float* dsc  = (float*)p;                 p += (size_t)n * 4;
    float* sA   = (float*)p;                 p += (size_t)n * Sdim * 4;
    float* sB   = (float*)p;                 p += (size_t)n * Sdim * 4;
    float* vA   = (float*)p;                 p += (size_t)n * NVdim * 4;
    float* vB   = (float*)p;                 p += (size_t)n * NVdim * 4;
    int* counts = (int*)p;                   p += (size_t)n * 4;
    int* cursor = (int*)p;                   p += (size_t)n * 4;
    int* rsL    = (int*)p;                   p += (size_t)(n + 4) * 4;
    int* rsG    = (int*)p;                   p += (size_t)(n + 4) * 4;
    int* eaL2   = (int*)p;                   p += (size_t)EL * 4;
    int* eaG2   = (int*)p;                   p += (size_t)EG * 4;
    p = alignup(p);
    int2* st2L  = (int2*)p;                  p += (size_t)EL * 8;
    int2* st2G  = (int2*)p;                  p += (size_t)EG * 8;
    p = alignup(p);
    unsigned short* wp     = (unsigned short*)p;  p += (size_t)10 * FINdim * Hdim * 2;
    p = alignup(p);
    unsigned short* bondbf = (unsigned short*)p;  p += 96 * 2;
    p = alignup(p);
    unsigned short* sbfA   = (unsigned short*)p;  p += (size_t)n * Sdim * 2;
    unsigned short* sbfB   = (unsigned short*)p;  p += (size_t)n * Sdim * 2;
    p = alignup(p);
    float4* rn4L = (float4*)p;               p += (size_t)EL * 16;
    float4* rn4G = (float4*)p;               p += (size_t)EG * 16;
    unsigned short* rbfbL = (unsigned short*)p;  p += (size_t)EL * 32 * 2;
    unsigned short* rbfbG = (unsigned short*)p;  p += (size_t)EG * 32 * 2;
    p = alignup(p);
    unsigned short* hm = (unsigned short*)p; p += (size_t)EG * 64 * 2;  // shared EL/EG
    unsigned short* hv = (unsigned short*)p; p += (size_t)EG * 32 * 2;

    float* out = (float*)d_out;

    // ---- precompute packed weights + init ----
    pack_kernel<<<(10 * FINdim * Hdim + 80 + 255) / 256, 256, 0, stream>>>(wm, bemb, wp, bondbf);
    temb_kernel<<<B, 64, 0, stream>>>(t, t_w1, t_b1, t_w2, t_b2, temb);
    node_init_kernel<<<(n * Sdim + 255) / 256, 256, 0, stream>>>(x, batch, aemb, temb, sA, sbfA, n);
    hipMemsetAsync(vA, 0, (size_t)n * NVdim * sizeof(float), stream);

    // ---- CSR build ----
    hipMemsetAsync(counts, 0, (size_t)n * sizeof(int), stream);
    count_kernel<<<(EL + 255) / 256, 256, 0, stream>>>(eil, EL, counts);
    scan_kernel<<<1, 256, 0, stream>>>(counts, n, rsL, cursor);
    scatter_kernel<<<(EL + 255) / 256, 256, 0, stream>>>(eil, eal, EL, cursor, st2L, eaL2);

    hipMemsetAsync(counts, 0, (size_t)n * sizeof(int), stream);
    count_kernel<<<(EG + 255) / 256, 256, 0, stream>>>(eig, EG, counts);
    scan_kernel<<<1, 256, 0, stream>>>(counts, n, rsG, cursor);
    scatter_kernel<<<(EG + 255) / 256, 256, 0, stream>>>(eig, eag, EG, cursor, st2G, eaG2);

    // ---- one-time edge geometry (layer-invariant) ----
    geom_kernel<<<(EL + 255) / 256, 256, 0, stream>>>(pos, st2L, eaL2, bondbf, rn4L, rbfbL, EL, 3.0f);
    geom_kernel<<<(EG + 255) / 256, 256, 0, stream>>>(pos, st2G, eaG2, bondbf, rn4G, rbfbG, EG, 10.0f);

    // ---- layers: edge-MLP GEMM then node aggregate/update ----
    float* s_cur = sA; float* s_nxt = sB;
    float* v_cur = vA; float* v_nxt = vB;
    unsigned short* sb_cur = sbfA; unsigned short* sb_nxt = sbfB;

    for (int l = 0; l < NLAYER; ++l) {
        for (int k = 0; k < 2; ++k) {
            int ls = l * 2 + k;
            const unsigned short* wpk = wp + (size_t)ls * FINdim * Hdim;
            const float* bgk = bm + (size_t)ls * Hdim;
            const float* wuk = wu + (size_t)ls * Sdim * Sdim;
            const float* buk = bu + (size_t)ls * Sdim;
            const int E          = (k == 0) ? EL : EG;
            const int2* st2k     = (k == 0) ? st2L : st2G;
            const int* rsk       = (k == 0) ? rsL : rsG;
            const float4* rn4k   = (k == 0) ? rn4L : rn4G;
            const unsigned short* rbfbk = (k == 0) ? rbfbL : rbfbG;

            edge_mlp_kernel<<<E / 128, 256, 0, stream>>>(
                sb_cur, st2k, rbfbk, wpk, bgk, hm, hv);
            node_agg_kernel<<<n, 64, 0, stream>>>(
                s_cur, s_nxt, sb_nxt, v_cur, v_nxt,
                rsk, st2k, (const float*)rn4k, hm, hv,
                wuk, buk, lng + (size_t)l * Sdim, lnb + (size_t)l * Sdim,
                (k == 1) ? 1 : 0);

            float* tmp = s_cur; s_cur = s_nxt; s_nxt = tmp;
            tmp = v_cur; v_cur = v_nxt; v_nxt = tmp;
            unsigned short* tb = sb_cur; sb_cur = sb_nxt; sb_nxt = tb;
        }
    }

    head1_kernel<<<n, 64, 0, stream>>>(s_cur, v_cur, wd, wo, dsc, out);
    head2_kernel<<<(n + 255) / 256, 256, 0, stream>>>(dsc, rsG, st2G, rn4G, out, n);
}

// Round 13
// 670.552 us; speedup vs baseline: 1.1946x; 1.0230x over previous
//
#include <hip/hip_runtime.h>
#include <math.h>

#define Sdim 64
#define Vdim 16
#define NLAYER 5
#define EDdim 16
#define RDdim 16
#define TDdim 64
#define FINdim 160   // 2*S + RD + ED
#define Hdim 96      // S + 2*V
#define NVdim 48     // 3*V

typedef __attribute__((ext_vector_type(8))) short bf16x8;
typedef __attribute__((ext_vector_type(4))) float f32x4;

__device__ __forceinline__ float silu_f(float x) {
    return x / (1.0f + __expf(-x));
}

__device__ __forceinline__ unsigned short f2bf(float x) {
    union { float f; unsigned u; } v; v.f = x;
    unsigned r = v.u + 0x7fffu + ((v.u >> 16) & 1u);
    return (unsigned short)(r >> 16);
}

__device__ __forceinline__ float bf2f(unsigned short u) {
    union { unsigned u; float f; } v; v.u = (unsigned)u << 16;
    return v.f;
}

// ---------------------------------------------------------------------------
// Pack W (10 layer-sets, [160][96] fp32) into MFMA B-fragment bf16 layout.
// ---------------------------------------------------------------------------
__global__ __launch_bounds__(256) void pack_kernel(
    const float* __restrict__ wm, const float* __restrict__ bemb,
    unsigned short* __restrict__ wp, unsigned short* __restrict__ bondbf)
{
    int idx = blockIdx.x * 256 + threadIdx.x;
    if (idx < 10 * FINdim * Hdim) {
        int ls = idx / (FINdim * Hdim), rem = idx % (FINdim * Hdim);
        int k = rem / Hdim, c = rem % Hdim;
        wp[(size_t)ls * FINdim * Hdim + ((size_t)(k >> 3) * Hdim + c) * 8 + (k & 7)] =
            f2bf(wm[idx]);
    } else if (idx < 10 * FINdim * Hdim + 80) {
        int i = idx - 10 * FINdim * Hdim;
        bondbf[i] = f2bf(bemb[i]);
    }
}

// ---------------------------------------------------------------------------
__global__ __launch_bounds__(64) void temb_kernel(
    const float* __restrict__ t, const float* __restrict__ w1, const float* __restrict__ b1,
    const float* __restrict__ w2, const float* __restrict__ b2, float* __restrict__ temb)
{
    int b = blockIdx.x, j = threadIdx.x;
    __shared__ float row[TDdim];
    __shared__ float hid[TDdim];
    row[j] = t[b * TDdim + j];
    __syncthreads();
    float h = b1[j];
    #pragma unroll 8
    for (int i = 0; i < TDdim; ++i) h = fmaf(row[i], w1[i * TDdim + j], h);
    h = silu_f(h);
    hid[j] = h;
    __syncthreads();
    float o = b2[j];
    #pragma unroll 8
    for (int i = 0; i < TDdim; ++i) o = fmaf(hid[i], w2[i * Sdim + j], o);
    temb[b * Sdim + j] = silu_f(o);
}

// ---------------------------------------------------------------------------
__global__ __launch_bounds__(256) void node_init_kernel(
    const int* __restrict__ x, const int* __restrict__ batch,
    const float* __restrict__ aemb, const float* __restrict__ temb,
    float* __restrict__ sfeat, unsigned short* __restrict__ sbf, int n)
{
    int idx = blockIdx.x * 256 + threadIdx.x;
    if (idx >= n * Sdim) return;
    int node = idx >> 6, j = idx & 63;
    int x0 = x[node * 3 + 0], x1 = x[node * 3 + 1], x2 = x[node * 3 + 2];
    float v = aemb[(0 * 16 + x0) * Sdim + j] + aemb[(16 + x1) * Sdim + j]
            + aemb[(32 + x2) * Sdim + j] + temb[batch[node] * Sdim + j];
    sfeat[idx] = v;
    sbf[idx]   = f2bf(v);
}

// ---------------------------------------------------------------------------
// CSR build for BOTH edge sets in one pass.
// Edge space is concatenated: local edges -> positions [0, EL),
// global edges -> positions [EL, EL+EG).  counts[tgt] (local) / counts[n+tgt].
// ---------------------------------------------------------------------------
__global__ __launch_bounds__(256) void count_all_kernel(
    const int* __restrict__ eil, int EL,
    const int* __restrict__ eig, int EG,
    int* __restrict__ counts, int n)
{
    int idx = blockIdx.x * 256 + threadIdx.x;
    if (idx < EL) {
        atomicAdd(&counts[eil[EL + idx]], 1);
    } else if (idx < EL + EG) {
        int j = idx - EL;
        atomicAdd(&counts[n + eig[EG + j]], 1);
    }
}

// single block; parallel scan over 2n counts (wave shuffle-scan + cross-wave)
__global__ __launch_bounds__(256) void scan_kernel(
    const int* __restrict__ counts, int n2,
    int* __restrict__ rowStart, int* __restrict__ cursor)
{
    __shared__ int wsum[4];
    int t = threadIdx.x;
    int chunk = n2 / 256;
    int base = t * chunk;
    int s = 0;
    for (int i = 0; i < chunk; ++i) s += counts[base + i];
    int lane = t & 63, w = t >> 6;
    int sc = s;
    #pragma unroll
    for (int off = 1; off < 64; off <<= 1) {
        int xv = __shfl_up(sc, off);
        if (lane >= off) sc += xv;
    }
    if (lane == 63) wsum[w] = sc;
    __syncthreads();
    int woff = 0;
    for (int i = 0; i < w; ++i) woff += wsum[i];
    int off = woff + sc - s;   // exclusive prefix for this thread's chunk
    for (int i = 0; i < chunk; ++i) {
        rowStart[base + i] = off;
        cursor[base + i]   = off;
        off += counts[base + i];
    }
    if (t == 255) rowStart[n2] = off;
}

// ---------------------------------------------------------------------------
// Fused scatter + geometry: one pass over all EL+EG edges.  Computes the CSR
// position p, then writes st2[p], rn4[p], rbfb[p] (rbf + bond bf16) directly.
// ---------------------------------------------------------------------------
__global__ __launch_bounds__(256) void scatgeom_kernel(
    const int* __restrict__ eil, const int* __restrict__ eal, int EL,
    const int* __restrict__ eig, const int* __restrict__ eag, int EG,
    int* __restrict__ cursor, int n,
    const float* __restrict__ pos, const unsigned short* __restrict__ bondbf,
    int2* __restrict__ st2, float4* __restrict__ rn4,
    unsigned short* __restrict__ rbfb)
{
    int idx = blockIdx.x * 256 + threadIdx.x;
    if (idx >= EL + EG) return;
    int src, tgt, ea, cbase;
    float cutoff;
    if (idx < EL) {
        src = eil[idx]; tgt = eil[EL + idx]; ea = eal[idx];
        cbase = 0; cutoff = 3.0f;
    } else {
        int j = idx - EL;
        src = eig[j]; tgt = eig[EG + j]; ea = eag[j];
        cbase = n; cutoff = 10.0f;
    }
    int p = atomicAdd(&cursor[cbase + tgt], 1);
    st2[p] = make_int2(src, tgt);

    float rx = pos[3*tgt]-pos[3*src], ry = pos[3*tgt+1]-pos[3*src+1], rz = pos[3*tgt+2]-pos[3*src+2];
    float d = sqrtf(fmaxf(rx*rx + ry*ry + rz*rz, 1e-6f));
    float invd = 1.0f / d;
    rn4[p] = make_float4(rx*invd, ry*invd, rz*invd, d);
    float env = (d < cutoff) ? 0.5f * (__cosf(3.14159265358979f * d / cutoff) + 1.0f) : 0.0f;
    float invw = (float)RDdim / cutoff;
    unsigned int pk[8];
    #pragma unroll
    for (int i2 = 0; i2 < 8; ++i2) {
        float c0 = cutoff * ((float)(2*i2)     / 15.0f);
        float c1 = cutoff * ((float)(2*i2 + 1) / 15.0f);
        float t0 = (d - c0) * invw, t1 = (d - c1) * invw;
        unsigned short b0 = f2bf(__expf(-0.5f * t0 * t0) * env);
        unsigned short b1 = f2bf(__expf(-0.5f * t1 * t1) * env);
        pk[i2] = (unsigned)b0 | ((unsigned)b1 << 16);
    }
    uint4* o = reinterpret_cast<uint4*>(rbfb + (size_t)p * 32);
    o[0] = make_uint4(pk[0], pk[1], pk[2], pk[3]);
    o[1] = make_uint4(pk[4], pk[5], pk[6], pk[7]);
    const uint4* bp = reinterpret_cast<const uint4*>(bondbf + ea * EDdim);
    o[2] = bp[0];
    o[3] = bp[1];
}

// ---------------------------------------------------------------------------
// Kernel A: edge MLP as a pure tall-skinny GEMM.  256 threads = 4 waves,
// each wave owns TWO independent 16-edge stripes (128 edges/block).
// W staged in LDS once; B-fragments ds_read per (kk,nt), shared by both
// stripes.  Latency hidden by occupancy.  Absolute edge index = eOff + ...
// ---------------------------------------------------------------------------
__global__ __launch_bounds__(256) void edge_mlp_kernel(
    const unsigned short* __restrict__ sbf_in,
    const int2* __restrict__ st2,
    const unsigned short* __restrict__ rbfb,
    const unsigned short* __restrict__ wpk,
    const float* __restrict__ bg,
    unsigned short* __restrict__ hm,
    unsigned short* __restrict__ hv,
    int eOff)
{
    __shared__ __align__(16) unsigned short Wl[FINdim * Hdim];  // 30720 B
    {
        const uint4* s4 = reinterpret_cast<const uint4*>(wpk);
        uint4* d4 = reinterpret_cast<uint4*>(Wl);
        for (int i = threadIdx.x; i < FINdim * Hdim / 8; i += 256) d4[i] = s4[i];
    }
    __syncthreads();

    const int lane = threadIdx.x & 63;
    const int wid  = threadIdx.x >> 6;
    const int l15 = lane & 15, l4 = lane >> 4;
    const int base0 = eOff + blockIdx.x * 128 + wid * 16;
    const int base1 = base0 + 64;

    const int2 st0 = st2[base0 + l15];
    const int2 st1 = st2[base1 + l15];
    bf16x8 a0[5], a1[5];
    {
        const unsigned short* sp = sbf_in + (size_t)st0.x * Sdim;
        const unsigned short* tp = sbf_in + (size_t)st0.y * Sdim;
        a0[0] = *reinterpret_cast<const bf16x8*>(sp + l4 * 8);
        a0[1] = *reinterpret_cast<const bf16x8*>(sp + 32 + l4 * 8);
        a0[2] = *reinterpret_cast<const bf16x8*>(tp + l4 * 8);
        a0[3] = *reinterpret_cast<const bf16x8*>(tp + 32 + l4 * 8);
        a0[4] = *reinterpret_cast<const bf16x8*>(rbfb + (size_t)(base0 + l15) * 32 + l4 * 8);
    }
    {
        const unsigned short* sp = sbf_in + (size_t)st1.x * Sdim;
        const unsigned short* tp = sbf_in + (size_t)st1.y * Sdim;
        a1[0] = *reinterpret_cast<const bf16x8*>(sp + l4 * 8);
        a1[1] = *reinterpret_cast<const bf16x8*>(sp + 32 + l4 * 8);
        a1[2] = *reinterpret_cast<const bf16x8*>(tp + l4 * 8);
        a1[3] = *reinterpret_cast<const bf16x8*>(tp + 32 + l4 * 8);
        a1[4] = *reinterpret_cast<const bf16x8*>(rbfb + (size_t)(base1 + l15) * 32 + l4 * 8);
    }

    f32x4 acc0[6], acc1[6];
    #pragma unroll
    for (int nt = 0; nt < 6; ++nt) {
        acc0[nt] = (f32x4){0.f, 0.f, 0.f, 0.f};
        acc1[nt] = (f32x4){0.f, 0.f, 0.f, 0.f};
    }
    #pragma unroll
    for (int kk = 0; kk < 5; ++kk) {
        #pragma unroll
        for (int nt = 0; nt < 6; ++nt) {
            bf16x8 b = *reinterpret_cast<const bf16x8*>(
                Wl + ((size_t)(kk * 4 + l4) * Hdim + nt * 16 + l15) * 8);
            acc0[nt] = __builtin_amdgcn_mfma_f32_16x16x32_bf16(a0[kk], b, acc0[nt], 0, 0, 0);
            acc1[nt] = __builtin_amdgcn_mfma_f32_16x16x32_bf16(a1[kk], b, acc1[nt], 0, 0, 0);
        }
    }

    // epilogue: bias + silu -> hm/hv (bf16).  D-layout: row = l4*4+r, col = nt*16+l15.
    #pragma unroll
    for (int nt = 0; nt < 6; ++nt) {
        const float bs = bg[nt * 16 + l15];
        #pragma unroll
        for (int r = 0; r < 4; ++r) {
            const int e0 = base0 + l4 * 4 + r;
            const int e1 = base1 + l4 * 4 + r;
            const unsigned short h0 = f2bf(silu_f(acc0[nt][r] + bs));
            const unsigned short h1 = f2bf(silu_f(acc1[nt][r] + bs));
            if (nt < 4) {
                hm[(size_t)e0 * 64 + nt * 16 + l15] = h0;
                hm[(size_t)e1 * 64 + nt * 16 + l15] = h1;
            } else {
                hv[(size_t)e0 * 32 + (nt - 4) * 16 + l15] = h0;
                hv[(size_t)e1 * 32 + (nt - 4) * 16 + l15] = h1;
            }
        }
    }
}

// ---------------------------------------------------------------------------
// Kernel B: segment-mean aggregation + node update.  ONE WAVE PER NODE,
// sums carried in registers, edge loop unrolled x2.  v_zero=1 for the first
// layer-set (v is identically 0: skip all v reads; vA memset eliminated).
// ---------------------------------------------------------------------------
__global__ __launch_bounds__(64) void node_agg_kernel(
    const float* __restrict__ s_in, float* __restrict__ s_out,
    unsigned short* __restrict__ sbf_out,
    const float* __restrict__ v_in, float* __restrict__ v_out,
    const int* __restrict__ rowStart, const int2* __restrict__ st2,
    const float* __restrict__ rn4f,
    const unsigned short* __restrict__ hm, const unsigned short* __restrict__ hv,
    const float* __restrict__ wu, const float* __restrict__ bu,
    const float* __restrict__ lng, const float* __restrict__ lnb,
    int do_ln, int v_zero)
{
    const int node = blockIdx.x;
    const int lane = threadIdx.x;
    const int l15 = lane & 15, dd = lane >> 4;
    const int lo = rowStart[node], hi = rowStart[node + 1];

    float msum0 = 0.0f, msum1 = 0.0f, vsum0 = 0.0f, vsum1 = 0.0f;
    int e = lo;
    for (; e + 1 < hi; e += 2) {
        msum0 += bf2f(hm[(size_t)e * 64 + lane]);
        msum1 += bf2f(hm[(size_t)(e + 1) * 64 + lane]);
        if (lane < NVdim) {
            float wv1a = bf2f(hv[(size_t)e * 32 + l15]);
            float wv2a = bf2f(hv[(size_t)e * 32 + 16 + l15]);
            float rnda = rn4f[(size_t)e * 4 + dd];
            float wv1b = bf2f(hv[(size_t)(e + 1) * 32 + l15]);
            float wv2b = bf2f(hv[(size_t)(e + 1) * 32 + 16 + l15]);
            float rndb = rn4f[(size_t)(e + 1) * 4 + dd];
            vsum0 = fmaf(rnda, wv2a, vsum0);
            vsum1 = fmaf(rndb, wv2b, vsum1);
            if (!v_zero) {
                float vva = v_in[(size_t)st2[e].x * NVdim + lane];
                float vvb = v_in[(size_t)st2[e + 1].x * NVdim + lane];
                vsum0 = fmaf(vva, wv1a, vsum0);
                vsum1 = fmaf(vvb, wv1b, vsum1);
            }
        }
    }
    if (e < hi) {
        msum0 += bf2f(hm[(size_t)e * 64 + lane]);
        if (lane < NVdim) {
            float wv1 = bf2f(hv[(size_t)e * 32 + l15]);
            float wv2 = bf2f(hv[(size_t)e * 32 + 16 + l15]);
            float rnd = rn4f[(size_t)e * 4 + dd];
            vsum0 = fmaf(rnd, wv2, vsum0);
            if (!v_zero) {
                float vv = v_in[(size_t)st2[e].x * NVdim + lane];
                vsum0 = fmaf(vv, wv1, vsum0);
            }
        }
    }
    float msum = msum0 + msum1;
    float vsum = vsum0 + vsum1;

    __shared__ float ag[64];
    const float ic = 1.0f / fmaxf((float)(hi - lo), 1.0f);
    ag[lane] = msum * ic;            // single wave: in-order LDS, no barrier

    float dot = 0.0f;
    #pragma unroll 8
    for (int i = 0; i < Sdim; ++i) dot = fmaf(ag[i], wu[i * Sdim + lane], dot);
    float sn = s_in[(size_t)node * Sdim + lane] + silu_f(dot + bu[lane]);
    if (do_ln) {
        float mm = sn;
        #pragma unroll
        for (int off = 32; off >= 1; off >>= 1) mm += __shfl_xor(mm, off);
        mm *= (1.0f / 64.0f);
        float dv = sn - mm;
        float var = dv * dv;
        #pragma unroll
        for (int off = 32; off >= 1; off >>= 1) var += __shfl_xor(var, off);
        var *= (1.0f / 64.0f);
        sn = dv * rsqrtf(var + 1e-5f) * lng[lane] + lnb[lane];
    }
    s_out[(size_t)node * Sdim + lane]   = sn;
    sbf_out[(size_t)node * Sdim + lane] = f2bf(sn);
    if (lane < NVdim) {
        float vprev = v_zero ? 0.0f : v_in[(size_t)node * NVdim + lane];
        v_out[(size_t)node * NVdim + lane] = vprev + vsum * ic;
    }
}

// ---------------------------------------------------------------------------
// Head
// ---------------------------------------------------------------------------
__global__ __launch_bounds__(64) void head1_kernel(
    const float* __restrict__ sfeat, const float* __restrict__ vfeat,
    const float* __restrict__ wd, const float* __restrict__ wo,
    float* __restrict__ dsc, float* __restrict__ out)
{
    int node = blockIdx.x, j = threadIdx.x;
    float val = silu_f(sfeat[(size_t)node * Sdim + j]) * wd[j];
    #pragma unroll
    for (int off = 32; off >= 1; off >>= 1) val += __shfl_xor(val, off);
    if (j == 0) dsc[node] = val;
    if (j < 3) {
        float a = 0.0f;
        #pragma unroll
        for (int m = 0; m < Vdim; ++m)
            a += vfeat[(size_t)node * NVdim + j * Vdim + m] * wo[m];
        out[(size_t)node * 3 + j] = a;
    }
}

// node-parallel over CSR-G; no atomics.  pos[src]-pos[tgt] = -rn.xyz * d.
__global__ __launch_bounds__(256) void head2_kernel(
    const float* __restrict__ dsc, const int* __restrict__ rsG,
    const int2* __restrict__ st2, const float4* __restrict__ rn4,
    float* __restrict__ out, int n)
{
    int t = blockIdx.x * 256 + threadIdx.x;
    if (t >= n) return;
    int lo = rsG[t], hi = rsG[t + 1];
    float dt = dsc[t];
    float ax = 0.f, ay = 0.f, az = 0.f;
    for (int e = lo; e < hi; ++e) {
        float w = dsc[st2[e].x] + dt;
        float4 rn = rn4[e];
        float wd_ = w * rn.w;
        ax -= wd_ * rn.x; ay -= wd_ * rn.y; az -= wd_ * rn.z;
    }
    out[3 * t + 0] += ax;
    out[3 * t + 1] += ay;
    out[3 * t + 2] += az;
}

// ---------------------------------------------------------------------------
extern "C" void kernel_launch(void* const* d_in, const int* in_sizes, int n_in,
                              void* d_out, int out_size, void* d_ws, size_t ws_size,
                              hipStream_t stream)
{
    const int*   x     = (const int*)d_in[0];
    const float* t     = (const float*)d_in[1];
    const float* pos   = (const float*)d_in[2];
    const int*   eil   = (const int*)d_in[3];
    const int*   eig   = (const int*)d_in[4];
    const int*   eal   = (const int*)d_in[5];
    const int*   eag   = (const int*)d_in[6];
    const int*   batch = (const int*)d_in[7];
    const float* aemb  = (const float*)d_in[8];
    const float* bemb  = (const float*)d_in[9];
    const float* t_w1  = (const float*)d_in[10];
    const float* t_b1  = (const float*)d_in[11];
    const float* t_w2  = (const float*)d_in[12];
    const float* t_b2  = (const float*)d_in[13];
    const float* wm    = (const float*)d_in[14];
    const float* bm    = (const float*)d_in[15];
    const float* wu    = (const float*)d_in[16];
    const float* bu    = (const float*)d_in[17];
    const float* lng   = (const float*)d_in[18];
    const float* lnb   = (const float*)d_in[19];
    const float* wd    = (const float*)d_in[20];
    const float* wo    = (const float*)d_in[21];

    const int n  = in_sizes[7];          // 16384
    const int B  = in_sizes[1] / TDdim;  // 64
    const int EL = in_sizes[3] / 2;      // 131072
    const int EG = in_sizes[4] / 2;      // 262144
    const int ET = EL + EG;

    // ---- workspace layout ----
    char* p = (char*)d_ws;
    auto alignup = [](char* q) { return (char*)(((size_t)q + 15) & ~(size_t)15); };

    float* temb = (float*)p;                 p += (size_t)B * Sdim * 4;
    float* dsc  = (float*)p;                 p += (size_t)n * 4;
    float* sA   = (float*)p;                 p += (size_t)n * Sdim * 4;
    float* sB   = (float*)p;                 p += (size_t)n * Sdim * 4;
    float* vA   = (float*)p;                 p += (size_t)n * NVdim * 4;
    float* vB   = (float*)p;                 p += (size_t)n * NVdim * 4;
    int* counts = (int*)p;                   p += (size_t)(2 * n) * 4;
    int* cursor = (int*)p;                   p += (size_t)(2 * n) * 4;
    int* rsAll  = (int*)p;                   p += (size_t)(2 * n + 4) * 4;
    p = alignup(p);
    int2* st2   = (int2*)p;                  p += (size_t)ET * 8;
    p = alignup(p);
    unsigned short* wp     = (unsigned short*)p;  p += (size_t)10 * FINdim * Hdim * 2;
    p = alignup(p);
    unsigned short* bondbf = (unsigned short*)p;  p += 96 * 2;
    p = alignup(p);
    unsigned short* sbfA   = (unsigned short*)p;  p += (size_t)n * Sdim * 2;
    unsigned short* sbfB   = (unsigned short*)p;  p += (size_t)n * Sdim * 2;
    p = alignup(p);
    float4* rn4 = (float4*)p;                p += (size_t)ET * 16;
    unsigned short* rbfb = (unsigned short*)p;    p += (size_t)ET * 32 * 2;
    p = alignup(p);
    unsigned short* hm = (unsigned short*)p; p += (size_t)ET * 64 * 2;
    unsigned short* hv = (unsigned short*)p; p += (size_t)ET * 32 * 2;

    float* out = (float*)d_out;

    // ---- precompute packed weights + init ----
    pack_kernel<<<(10 * FINdim * Hdim + 80 + 255) / 256, 256, 0, stream>>>(wm, bemb, wp, bondbf);
    temb_kernel<<<B, 64, 0, stream>>>(t, t_w1, t_b1, t_w2, t_b2, temb);
    node_init_kernel<<<(n * Sdim + 255) / 256, 256, 0, stream>>>(x, batch, aemb, temb, sA, sbfA, n);

    // ---- combined CSR build + geometry (both edge sets, one pass each) ----
    hipMemsetAsync(counts, 0, (size_t)(2 * n) * sizeof(int), stream);
    count_all_kernel<<<(ET + 255) / 256, 256, 0, stream>>>(eil, EL, eig, EG, counts, n);
    scan_kernel<<<1, 256, 0, stream>>>(counts, 2 * n, rsAll, cursor);
    scatgeom_kernel<<<(ET + 255) / 256, 256, 0, stream>>>(
        eil, eal, EL, eig, eag, EG, cursor, n, pos, bondbf, st2, rn4, rbfb);

    // ---- layers: edge-MLP GEMM then node aggregate/update ----
    float* s_cur = sA; float* s_nxt = sB;
    float* v_cur = vA; float* v_nxt = vB;
    unsigned short* sb_cur = sbfA; unsigned short* sb_nxt = sbfB;

    for (int l = 0; l < NLAYER; ++l) {
        for (int k = 0; k < 2; ++k) {
            int ls = l * 2 + k;
            const unsigned short* wpk = wp + (size_t)ls * FINdim * Hdim;
            const float* bgk = bm + (size_t)ls * Hdim;
            const float* wuk = wu + (size_t)ls * Sdim * Sdim;
            const float* buk = bu + (size_t)ls * Sdim;
            const int E    = (k == 0) ? EL : EG;
            const int eOff = (k == 0) ? 0 : EL;
            const int* rsk = (k == 0) ? rsAll : rsAll + n;
            const int v_zero = (l == 0 && k == 0) ? 1 : 0;

            edge_mlp_kernel<<<E / 128, 256, 0, stream>>>(
                sb_cur, st2, rbfb, wpk, bgk, hm, hv, eOff);
            node_agg_kernel<<<n, 64, 0, stream>>>(
                s_cur, s_nxt, sb_nxt, v_cur, v_nxt,
                rsk, st2, (const float*)rn4, hm, hv,
                wuk, buk, lng + (size_t)l * Sdim, lnb + (size_t)l * Sdim,
                (k == 1) ? 1 : 0, v_zero);

            float* tmp = s_cur; s_cur = s_nxt; s_nxt = tmp;
            tmp = v_cur; v_cur = v_nxt; v_nxt = tmp;
            unsigned short* tb = sb_cur; sb_cur = sb_nxt; sb_nxt = tb;
        }
    }

    head1_kernel<<<n, 64, 0, stream>>>(s_cur, v_cur, wd, wo, dsc, out);
    head2_kernel<<<(n + 255) / 256, 256, 0, stream>>>(dsc, rsAll + n, st2, rn4, out, n);
}

// Round 14
// 606.275 us; speedup vs baseline: 1.3213x; 1.1060x over previous
//
#include <hip/hip_runtime.h>
#include <math.h>

#define Sdim 64
#define Vdim 16
#define NLAYER 5
#define EDdim 16
#define RDdim 16
#define TDdim 64
#define FINdim 160   // 2*S + RD + ED
#define Hdim 96      // S + 2*V
#define NVdim 48     // 3*V

typedef __attribute__((ext_vector_type(8))) short bf16x8;
typedef __attribute__((ext_vector_type(4))) float f32x4;

__device__ __forceinline__ float silu_f(float x) {
    return x / (1.0f + __expf(-x));
}

__device__ __forceinline__ unsigned short f2bf(float x) {
    union { float f; unsigned u; } v; v.f = x;
    unsigned r = v.u + 0x7fffu + ((v.u >> 16) & 1u);
    return (unsigned short)(r >> 16);
}

__device__ __forceinline__ float bf2f(unsigned short u) {
    union { unsigned u; float f; } v; v.u = (unsigned)u << 16;
    return v.f;
}

// ---------------------------------------------------------------------------
// Pack W (10 layer-sets, [160][96] fp32) into MFMA B-fragment bf16 layout.
// ---------------------------------------------------------------------------
__global__ __launch_bounds__(256) void pack_kernel(
    const float* __restrict__ wm, const float* __restrict__ bemb,
    unsigned short* __restrict__ wp, unsigned short* __restrict__ bondbf)
{
    int idx = blockIdx.x * 256 + threadIdx.x;
    if (idx < 10 * FINdim * Hdim) {
        int ls = idx / (FINdim * Hdim), rem = idx % (FINdim * Hdim);
        int k = rem / Hdim, c = rem % Hdim;
        wp[(size_t)ls * FINdim * Hdim + ((size_t)(k >> 3) * Hdim + c) * 8 + (k & 7)] =
            f2bf(wm[idx]);
    } else if (idx < 10 * FINdim * Hdim + 80) {
        int i = idx - 10 * FINdim * Hdim;
        bondbf[i] = f2bf(bemb[i]);
    }
}

// ---------------------------------------------------------------------------
__global__ __launch_bounds__(64) void temb_kernel(
    const float* __restrict__ t, const float* __restrict__ w1, const float* __restrict__ b1,
    const float* __restrict__ w2, const float* __restrict__ b2, float* __restrict__ temb)
{
    int b = blockIdx.x, j = threadIdx.x;
    __shared__ float row[TDdim];
    __shared__ float hid[TDdim];
    row[j] = t[b * TDdim + j];
    __syncthreads();
    float h = b1[j];
    #pragma unroll 8
    for (int i = 0; i < TDdim; ++i) h = fmaf(row[i], w1[i * TDdim + j], h);
    h = silu_f(h);
    hid[j] = h;
    __syncthreads();
    float o = b2[j];
    #pragma unroll 8
    for (int i = 0; i < TDdim; ++i) o = fmaf(hid[i], w2[i * Sdim + j], o);
    temb[b * Sdim + j] = silu_f(o);
}

// ---------------------------------------------------------------------------
__global__ __launch_bounds__(256) void node_init_kernel(
    const int* __restrict__ x, const int* __restrict__ batch,
    const float* __restrict__ aemb, const float* __restrict__ temb,
    float* __restrict__ sfeat, unsigned short* __restrict__ sbf, int n)
{
    int idx = blockIdx.x * 256 + threadIdx.x;
    if (idx >= n * Sdim) return;
    int node = idx >> 6, j = idx & 63;
    int x0 = x[node * 3 + 0], x1 = x[node * 3 + 1], x2 = x[node * 3 + 2];
    float v = aemb[(0 * 16 + x0) * Sdim + j] + aemb[(16 + x1) * Sdim + j]
            + aemb[(32 + x2) * Sdim + j] + temb[batch[node] * Sdim + j];
    sfeat[idx] = v;
    sbf[idx]   = f2bf(v);
}

// ---------------------------------------------------------------------------
// CSR build for BOTH edge sets in one pass (concatenated edge space).
// ---------------------------------------------------------------------------
__global__ __launch_bounds__(256) void count_all_kernel(
    const int* __restrict__ eil, int EL,
    const int* __restrict__ eig, int EG,
    int* __restrict__ counts, int n)
{
    int idx = blockIdx.x * 256 + threadIdx.x;
    if (idx < EL) {
        atomicAdd(&counts[eil[EL + idx]], 1);
    } else if (idx < EL + EG) {
        int j = idx - EL;
        atomicAdd(&counts[n + eig[EG + j]], 1);
    }
}

// single block, 1024 threads; chunk=32 kept in REGISTERS (int4 x8).
// Phase1: vector loads + per-thread sum; wave shuffle-scan; 16-wave LDS
// offsets.  Phase2: 32-step serial add from registers (no re-read).
__global__ __launch_bounds__(1024) void scan_kernel(
    const int* __restrict__ counts, int n2,
    int* __restrict__ rowStart, int* __restrict__ cursor)
{
    __shared__ int wsum[16];
    const int t = threadIdx.x;
    const int chunk = n2 >> 10;            // 32
    const int base = t * chunk;

    int4 c[8];
    const int4* c4 = reinterpret_cast<const int4*>(counts + base);
    #pragma unroll
    for (int i = 0; i < 8; ++i) c[i] = c4[i];

    int s = 0;
    #pragma unroll
    for (int i = 0; i < 8; ++i) s += c[i].x + c[i].y + c[i].z + c[i].w;

    const int lane = t & 63, w = t >> 6;
    int sc = s;
    #pragma unroll
    for (int off = 1; off < 64; off <<= 1) {
        int xv = __shfl_up(sc, off);
        if (lane >= off) sc += xv;
    }
    if (lane == 63) wsum[w] = sc;
    __syncthreads();
    int woff = 0;
    for (int i = 0; i < w; ++i) woff += wsum[i];
    int off = woff + sc - s;               // exclusive prefix of this chunk

    #pragma unroll
    for (int i = 0; i < 8; ++i) {
        int v0 = c[i].x, v1 = c[i].y, v2 = c[i].z, v3 = c[i].w;
        int o0 = off, o1 = o0 + v0, o2 = o1 + v1, o3 = o2 + v2;
        *reinterpret_cast<int4*>(rowStart + base + i * 4) = make_int4(o0, o1, o2, o3);
        *reinterpret_cast<int4*>(cursor   + base + i * 4) = make_int4(o0, o1, o2, o3);
        off = o3 + v3;
    }
    if (t == 1023) rowStart[n2] = off;
}

// ---------------------------------------------------------------------------
// Fused scatter + geometry: one pass over all EL+EG edges.
// ---------------------------------------------------------------------------
__global__ __launch_bounds__(256) void scatgeom_kernel(
    const int* __restrict__ eil, const int* __restrict__ eal, int EL,
    const int* __restrict__ eig, const int* __restrict__ eag, int EG,
    int* __restrict__ cursor, int n,
    const float* __restrict__ pos, const unsigned short* __restrict__ bondbf,
    int2* __restrict__ st2, float4* __restrict__ rn4,
    unsigned short* __restrict__ rbfb)
{
    int idx = blockIdx.x * 256 + threadIdx.x;
    if (idx >= EL + EG) return;
    int src, tgt, ea, cbase;
    float cutoff;
    if (idx < EL) {
        src = eil[idx]; tgt = eil[EL + idx]; ea = eal[idx];
        cbase = 0; cutoff = 3.0f;
    } else {
        int j = idx - EL;
        src = eig[j]; tgt = eig[EG + j]; ea = eag[j];
        cbase = n; cutoff = 10.0f;
    }
    int p = atomicAdd(&cursor[cbase + tgt], 1);
    st2[p] = make_int2(src, tgt);

    float rx = pos[3*tgt]-pos[3*src], ry = pos[3*tgt+1]-pos[3*src+1], rz = pos[3*tgt+2]-pos[3*src+2];
    float d = sqrtf(fmaxf(rx*rx + ry*ry + rz*rz, 1e-6f));
    float invd = 1.0f / d;
    rn4[p] = make_float4(rx*invd, ry*invd, rz*invd, d);
    float env = (d < cutoff) ? 0.5f * (__cosf(3.14159265358979f * d / cutoff) + 1.0f) : 0.0f;
    float invw = (float)RDdim / cutoff;
    unsigned int pk[8];
    #pragma unroll
    for (int i2 = 0; i2 < 8; ++i2) {
        float c0 = cutoff * ((float)(2*i2)     / 15.0f);
        float c1 = cutoff * ((float)(2*i2 + 1) / 15.0f);
        float t0 = (d - c0) * invw, t1 = (d - c1) * invw;
        unsigned short b0 = f2bf(__expf(-0.5f * t0 * t0) * env);
        unsigned short b1 = f2bf(__expf(-0.5f * t1 * t1) * env);
        pk[i2] = (unsigned)b0 | ((unsigned)b1 << 16);
    }
    uint4* o = reinterpret_cast<uint4*>(rbfb + (size_t)p * 32);
    o[0] = make_uint4(pk[0], pk[1], pk[2], pk[3]);
    o[1] = make_uint4(pk[4], pk[5], pk[6], pk[7]);
    const uint4* bp = reinterpret_cast<const uint4*>(bondbf + ea * EDdim);
    o[2] = bp[0];
    o[3] = bp[1];
}

// ---------------------------------------------------------------------------
// Kernel A: edge MLP as a pure tall-skinny GEMM (unchanged from r13).
// ---------------------------------------------------------------------------
__global__ __launch_bounds__(256) void edge_mlp_kernel(
    const unsigned short* __restrict__ sbf_in,
    const int2* __restrict__ st2,
    const unsigned short* __restrict__ rbfb,
    const unsigned short* __restrict__ wpk,
    const float* __restrict__ bg,
    unsigned short* __restrict__ hm,
    unsigned short* __restrict__ hv,
    int eOff)
{
    __shared__ __align__(16) unsigned short Wl[FINdim * Hdim];  // 30720 B
    {
        const uint4* s4 = reinterpret_cast<const uint4*>(wpk);
        uint4* d4 = reinterpret_cast<uint4*>(Wl);
        for (int i = threadIdx.x; i < FINdim * Hdim / 8; i += 256) d4[i] = s4[i];
    }
    __syncthreads();

    const int lane = threadIdx.x & 63;
    const int wid  = threadIdx.x >> 6;
    const int l15 = lane & 15, l4 = lane >> 4;
    const int base0 = eOff + blockIdx.x * 128 + wid * 16;
    const int base1 = base0 + 64;

    const int2 st0 = st2[base0 + l15];
    const int2 st1 = st2[base1 + l15];
    bf16x8 a0[5], a1[5];
    {
        const unsigned short* sp = sbf_in + (size_t)st0.x * Sdim;
        const unsigned short* tp = sbf_in + (size_t)st0.y * Sdim;
        a0[0] = *reinterpret_cast<const bf16x8*>(sp + l4 * 8);
        a0[1] = *reinterpret_cast<const bf16x8*>(sp + 32 + l4 * 8);
        a0[2] = *reinterpret_cast<const bf16x8*>(tp + l4 * 8);
        a0[3] = *reinterpret_cast<const bf16x8*>(tp + 32 + l4 * 8);
        a0[4] = *reinterpret_cast<const bf16x8*>(rbfb + (size_t)(base0 + l15) * 32 + l4 * 8);
    }
    {
        const unsigned short* sp = sbf_in + (size_t)st1.x * Sdim;
        const unsigned short* tp = sbf_in + (size_t)st1.y * Sdim;
        a1[0] = *reinterpret_cast<const bf16x8*>(sp + l4 * 8);
        a1[1] = *reinterpret_cast<const bf16x8*>(sp + 32 + l4 * 8);
        a1[2] = *reinterpret_cast<const bf16x8*>(tp + l4 * 8);
        a1[3] = *reinterpret_cast<const bf16x8*>(tp + 32 + l4 * 8);
        a1[4] = *reinterpret_cast<const bf16x8*>(rbfb + (size_t)(base1 + l15) * 32 + l4 * 8);
    }

    f32x4 acc0[6], acc1[6];
    #pragma unroll
    for (int nt = 0; nt < 6; ++nt) {
        acc0[nt] = (f32x4){0.f, 0.f, 0.f, 0.f};
        acc1[nt] = (f32x4){0.f, 0.f, 0.f, 0.f};
    }
    #pragma unroll
    for (int kk = 0; kk < 5; ++kk) {
        #pragma unroll
        for (int nt = 0; nt < 6; ++nt) {
            bf16x8 b = *reinterpret_cast<const bf16x8*>(
                Wl + ((size_t)(kk * 4 + l4) * Hdim + nt * 16 + l15) * 8);
            acc0[nt] = __builtin_amdgcn_mfma_f32_16x16x32_bf16(a0[kk], b, acc0[nt], 0, 0, 0);
            acc1[nt] = __builtin_amdgcn_mfma_f32_16x16x32_bf16(a1[kk], b, acc1[nt], 0, 0, 0);
        }
    }

    #pragma unroll
    for (int nt = 0; nt < 6; ++nt) {
        const float bs = bg[nt * 16 + l15];
        #pragma unroll
        for (int r = 0; r < 4; ++r) {
            const int e0 = base0 + l4 * 4 + r;
            const int e1 = base1 + l4 * 4 + r;
            const unsigned short h0 = f2bf(silu_f(acc0[nt][r] + bs));
            const unsigned short h1 = f2bf(silu_f(acc1[nt][r] + bs));
            if (nt < 4) {
                hm[(size_t)e0 * 64 + nt * 16 + l15] = h0;
                hm[(size_t)e1 * 64 + nt * 16 + l15] = h1;
            } else {
                hv[(size_t)e0 * 32 + (nt - 4) * 16 + l15] = h0;
                hv[(size_t)e1 * 32 + (nt - 4) * 16 + l15] = h1;
            }
        }
    }
}

// ---------------------------------------------------------------------------
// Kernel B: segment-mean aggregation + node update; optional fused head1
// (dsc + v-projection) on the final layer-set.
// ---------------------------------------------------------------------------
__global__ __launch_bounds__(64) void node_agg_kernel(
    const float* __restrict__ s_in, float* __restrict__ s_out,
    unsigned short* __restrict__ sbf_out,
    const float* __restrict__ v_in, float* __restrict__ v_out,
    const int* __restrict__ rowStart, const int2* __restrict__ st2,
    const float* __restrict__ rn4f,
    const unsigned short* __restrict__ hm, const unsigned short* __restrict__ hv,
    const float* __restrict__ wu, const float* __restrict__ bu,
    const float* __restrict__ lng, const float* __restrict__ lnb,
    int do_ln, int v_zero,
    int do_head, const float* __restrict__ wd, const float* __restrict__ wo,
    float* __restrict__ dsc, float* __restrict__ out)
{
    const int node = blockIdx.x;
    const int lane = threadIdx.x;
    const int l15 = lane & 15, dd = lane >> 4;
    const int lo = rowStart[node], hi = rowStart[node + 1];

    float msum0 = 0.0f, msum1 = 0.0f, vsum0 = 0.0f, vsum1 = 0.0f;
    int e = lo;
    for (; e + 1 < hi; e += 2) {
        msum0 += bf2f(hm[(size_t)e * 64 + lane]);
        msum1 += bf2f(hm[(size_t)(e + 1) * 64 + lane]);
        if (lane < NVdim) {
            float wv1a = bf2f(hv[(size_t)e * 32 + l15]);
            float wv2a = bf2f(hv[(size_t)e * 32 + 16 + l15]);
            float rnda = rn4f[(size_t)e * 4 + dd];
            float wv1b = bf2f(hv[(size_t)(e + 1) * 32 + l15]);
            float wv2b = bf2f(hv[(size_t)(e + 1) * 32 + 16 + l15]);
            float rndb = rn4f[(size_t)(e + 1) * 4 + dd];
            vsum0 = fmaf(rnda, wv2a, vsum0);
            vsum1 = fmaf(rndb, wv2b, vsum1);
            if (!v_zero) {
                float vva = v_in[(size_t)st2[e].x * NVdim + lane];
                float vvb = v_in[(size_t)st2[e + 1].x * NVdim + lane];
                vsum0 = fmaf(vva, wv1a, vsum0);
                vsum1 = fmaf(vvb, wv1b, vsum1);
            }
        }
    }
    if (e < hi) {
        msum0 += bf2f(hm[(size_t)e * 64 + lane]);
        if (lane < NVdim) {
            float wv1 = bf2f(hv[(size_t)e * 32 + l15]);
            float wv2 = bf2f(hv[(size_t)e * 32 + 16 + l15]);
            float rnd = rn4f[(size_t)e * 4 + dd];
            vsum0 = fmaf(rnd, wv2, vsum0);
            if (!v_zero) {
                float vv = v_in[(size_t)st2[e].x * NVdim + lane];
                vsum0 = fmaf(vv, wv1, vsum0);
            }
        }
    }
    float msum = msum0 + msum1;
    float vsum = vsum0 + vsum1;

    __shared__ float ag[64];
    const float ic = 1.0f / fmaxf((float)(hi - lo), 1.0f);
    ag[lane] = msum * ic;            // single wave: in-order LDS, no barrier

    float dot = 0.0f;
    #pragma unroll 8
    for (int i = 0; i < Sdim; ++i) dot = fmaf(ag[i], wu[i * Sdim + lane], dot);
    float sn = s_in[(size_t)node * Sdim + lane] + silu_f(dot + bu[lane]);
    if (do_ln) {
        float mm = sn;
        #pragma unroll
        for (int off = 32; off >= 1; off >>= 1) mm += __shfl_xor(mm, off);
        mm *= (1.0f / 64.0f);
        float dv = sn - mm;
        float var = dv * dv;
        #pragma unroll
        for (int off = 32; off >= 1; off >>= 1) var += __shfl_xor(var, off);
        var *= (1.0f / 64.0f);
        sn = dv * rsqrtf(var + 1e-5f) * lng[lane] + lnb[lane];
    }
    s_out[(size_t)node * Sdim + lane]   = sn;
    sbf_out[(size_t)node * Sdim + lane] = f2bf(sn);
    float vnew = 0.0f;
    if (lane < NVdim) {
        float vprev = v_zero ? 0.0f : v_in[(size_t)node * NVdim + lane];
        vnew = vprev + vsum * ic;
        v_out[(size_t)node * NVdim + lane] = vnew;
    }

    if (do_head) {
        // dsc[node] = sum_j silu(sn_j) * wd_j   (full-wave reduce)
        float val = silu_f(sn) * wd[lane];
        #pragma unroll
        for (int off = 32; off >= 1; off >>= 1) val += __shfl_xor(val, off);
        if (lane == 0) dsc[node] = val;
        // out[node][d] = sum_m vnew[d*16+m] * wo[m]  (16-lane group reduce)
        float contrib = (lane < NVdim) ? vnew * wo[l15] : 0.0f;
        #pragma unroll
        for (int off = 1; off < 16; off <<= 1) contrib += __shfl_xor(contrib, off);
        if (lane < NVdim && l15 == 0) out[(size_t)node * 3 + dd] = contrib;
    }
}

// ---------------------------------------------------------------------------
// head2: node-parallel over CSR-G; no atomics.  pos[src]-pos[tgt] = -rn*d.
// ---------------------------------------------------------------------------
__global__ __launch_bounds__(256) void head2_kernel(
    const float* __restrict__ dsc, const int* __restrict__ rsG,
    const int2* __restrict__ st2, const float4* __restrict__ rn4,
    float* __restrict__ out, int n)
{
    int t = blockIdx.x * 256 + threadIdx.x;
    if (t >= n) return;
    int lo = rsG[t], hi = rsG[t + 1];
    float dt = dsc[t];
    float ax = 0.f, ay = 0.f, az = 0.f;
    for (int e = lo; e < hi; ++e) {
        float w = dsc[st2[e].x] + dt;
        float4 rn = rn4[e];
        float wd_ = w * rn.w;
        ax -= wd_ * rn.x; ay -= wd_ * rn.y; az -= wd_ * rn.z;
    }
    out[3 * t + 0] += ax;
    out[3 * t + 1] += ay;
    out[3 * t + 2] += az;
}

// ---------------------------------------------------------------------------
extern "C" void kernel_launch(void* const* d_in, const int* in_sizes, int n_in,
                              void* d_out, int out_size, void* d_ws, size_t ws_size,
                              hipStream_t stream)
{
    const int*   x     = (const int*)d_in[0];
    const float* t     = (const float*)d_in[1];
    const float* pos   = (const float*)d_in[2];
    const int*   eil   = (const int*)d_in[3];
    const int*   eig   = (const int*)d_in[4];
    const int*   eal   = (const int*)d_in[5];
    const int*   eag   = (const int*)d_in[6];
    const int*   batch = (const int*)d_in[7];
    const float* aemb  = (const float*)d_in[8];
    const float* bemb  = (const float*)d_in[9];
    const float* t_w1  = (const float*)d_in[10];
    const float* t_b1  = (const float*)d_in[11];
    const float* t_w2  = (const float*)d_in[12];
    const float* t_b2  = (const float*)d_in[13];
    const float* wm    = (const float*)d_in[14];
    const float* bm    = (const float*)d_in[15];
    const float* wu    = (const float*)d_in[16];
    const float* bu    = (const float*)d_in[17];
    const float* lng   = (const float*)d_in[18];
    const float* lnb   = (const float*)d_in[19];
    const float* wd    = (const float*)d_in[20];
    const float* wo    = (const float*)d_in[21];

    const int n  = in_sizes[7];          // 16384
    const int B  = in_sizes[1] / TDdim;  // 64
    const int EL = in_sizes[3] / 2;      // 131072
    const int EG = in_sizes[4] / 2;      // 262144
    const int ET = EL + EG;

    // ---- workspace layout ----
    char* p = (char*)d_ws;
    auto alignup = [](char* q) { return (char*)(((size_t)q + 15) & ~(size_t)15); };

    float* temb = (float*)p;                 p += (size_t)B * Sdim * 4;
    float* dsc  = (float*)p;                 p += (size_t)n * 4;
    float* sA   = (float*)p;                 p += (size_t)n * Sdim * 4;
    float* sB   = (float*)p;                 p += (size_t)n * Sdim * 4;
    float* vA   = (float*)p;                 p += (size_t)n * NVdim * 4;
    float* vB   = (float*)p;                 p += (size_t)n * NVdim * 4;
    int* counts = (int*)p;                   p += (size_t)(2 * n) * 4;
    int* cursor = (int*)p;                   p += (size_t)(2 * n) * 4;
    int* rsAll  = (int*)p;                   p += (size_t)(2 * n + 4) * 4;
    p = alignup(p);
    int2* st2   = (int2*)p;                  p += (size_t)ET * 8;
    p = alignup(p);
    unsigned short* wp     = (unsigned short*)p;  p += (size_t)10 * FINdim * Hdim * 2;
    p = alignup(p);
    unsigned short* bondbf = (unsigned short*)p;  p += 96 * 2;
    p = alignup(p);
    unsigned short* sbfA   = (unsigned short*)p;  p += (size_t)n * Sdim * 2;
    unsigned short* sbfB   = (unsigned short*)p;  p += (size_t)n * Sdim * 2;
    p = alignup(p);
    float4* rn4 = (float4*)p;                p += (size_t)ET * 16;
    unsigned short* rbfb = (unsigned short*)p;    p += (size_t)ET * 32 * 2;
    p = alignup(p);
    unsigned short* hm = (unsigned short*)p; p += (size_t)ET * 64 * 2;
    unsigned short* hv = (unsigned short*)p; p += (size_t)ET * 32 * 2;

    float* out = (float*)d_out;

    // ---- precompute packed weights + init ----
    pack_kernel<<<(10 * FINdim * Hdim + 80 + 255) / 256, 256, 0, stream>>>(wm, bemb, wp, bondbf);
    temb_kernel<<<B, 64, 0, stream>>>(t, t_w1, t_b1, t_w2, t_b2, temb);
    node_init_kernel<<<(n * Sdim + 255) / 256, 256, 0, stream>>>(x, batch, aemb, temb, sA, sbfA, n);

    // ---- combined CSR build + geometry (both edge sets, one pass each) ----
    hipMemsetAsync(counts, 0, (size_t)(2 * n) * sizeof(int), stream);
    count_all_kernel<<<(ET + 255) / 256, 256, 0, stream>>>(eil, EL, eig, EG, counts, n);
    scan_kernel<<<1, 1024, 0, stream>>>(counts, 2 * n, rsAll, cursor);
    scatgeom_kernel<<<(ET + 255) / 256, 256, 0, stream>>>(
        eil, eal, EL, eig, eag, EG, cursor, n, pos, bondbf, st2, rn4, rbfb);

    // ---- layers: edge-MLP GEMM then node aggregate/update ----
    float* s_cur = sA; float* s_nxt = sB;
    float* v_cur = vA; float* v_nxt = vB;
    unsigned short* sb_cur = sbfA; unsigned short* sb_nxt = sbfB;

    for (int l = 0; l < NLAYER; ++l) {
        for (int k = 0; k < 2; ++k) {
            int ls = l * 2 + k;
            const unsigned short* wpk = wp + (size_t)ls * FINdim * Hdim;
            const float* bgk = bm + (size_t)ls * Hdim;
            const float* wuk = wu + (size_t)ls * Sdim * Sdim;
            const float* buk = bu + (size_t)ls * Sdim;
            const int E    = (k == 0) ? EL : EG;
            const int eOff = (k == 0) ? 0 : EL;
            const int* rsk = (k == 0) ? rsAll : rsAll + n;
            const int v_zero = (l == 0 && k == 0) ? 1 : 0;
            const int is_last = (l == NLAYER - 1 && k == 1) ? 1 : 0;

            edge_mlp_kernel<<<E / 128, 256, 0, stream>>>(
                sb_cur, st2, rbfb, wpk, bgk, hm, hv, eOff);
            node_agg_kernel<<<n, 64, 0, stream>>>(
                s_cur, s_nxt, sb_nxt, v_cur, v_nxt,
                rsk, st2, (const float*)rn4, hm, hv,
                wuk, buk, lng + (size_t)l * Sdim, lnb + (size_t)l * Sdim,
                (k == 1) ? 1 : 0, v_zero,
                is_last, wd, wo, dsc, out);

            float* tmp = s_cur; s_cur = s_nxt; s_nxt = tmp;
            tmp = v_cur; v_cur = v_nxt; v_nxt = tmp;
            unsigned short* tb = sb_cur; sb_cur = sb_nxt; sb_nxt = tb;
        }
    }

    head2_kernel<<<(n + 255) / 256, 256, 0, stream>>>(dsc, rsAll + n, st2, rn4, out, n);
}